// Round 2
// baseline (456.129 us; speedup 1.0000x reference)
//
#include <hip/hip_runtime.h>
#include <math.h>

typedef unsigned short u16;
typedef __attribute__((ext_vector_type(4))) float f32x4;
typedef __attribute__((ext_vector_type(8))) short s16x8;

__device__ __forceinline__ u16 f2bf(float f){
  unsigned u = __builtin_bit_cast(unsigned, f);
  u += 0x7fffu + ((u >> 16) & 1u);
  return (u16)(u >> 16);
}
__device__ __forceinline__ float bf2f(u16 h){
  unsigned u = ((unsigned)h) << 16;
  return __builtin_bit_cast(float, u);
}
__device__ __forceinline__ f32x4 mfma16(s16x8 a, s16x8 b, f32x4 c){
  return __builtin_amdgcn_mfma_f32_16x16x32_bf16(a, b, c, 0, 0, 0);
}

// ---------------- split x -> bf16 hi/lo ----------------
__global__ __launch_bounds__(256) void k_split(const float* __restrict__ x,
    u16* __restrict__ xh, u16* __restrict__ xl, int n4){
  int id = blockIdx.x*256 + threadIdx.x;
  if (id >= n4) return;
  float4 v = ((const float4*)x)[id];
  float vv[4] = {v.x, v.y, v.z, v.w};
  u16 hh[4], ll[4];
  #pragma unroll
  for (int i=0;i<4;++i){ hh[i] = f2bf(vv[i]); ll[i] = f2bf(vv[i] - bf2f(hh[i])); }
  ((ushort4*)xh)[id] = make_ushort4(hh[0],hh[1],hh[2],hh[3]);
  ((ushort4*)xl)[id] = make_ushort4(ll[0],ll[1],ll[2],ll[3]);
}

// ------------- transpose + split: in[R][C] f32 -> out[C][R] bf16 hi/lo -------------
__global__ __launch_bounds__(256) void k_tsplit(const float* __restrict__ in,
    u16* __restrict__ oh, u16* __restrict__ ol, int R, int C){
  __shared__ float tile[32][33];
  int tx = threadIdx.x & 31, ty = threadIdx.x >> 5;
  int c0 = blockIdx.x*32, r0 = blockIdx.y*32;
  #pragma unroll
  for (int rr=0; rr<4; ++rr){
    int row = ty*4 + rr;
    tile[row][tx] = in[(size_t)(r0+row)*C + (c0+tx)];
  }
  __syncthreads();
  #pragma unroll
  for (int rr=0; rr<4; ++rr){
    int row = ty*4 + rr;
    float v = tile[tx][row];
    size_t o = (size_t)(c0+row)*R + (r0+tx);
    u16 hh = f2bf(v);
    oh[o] = hh; ol[o] = f2bf(v - bf2f(hh));
  }
}

// ------------- split-bf16 GEMM: C[M][N] = A[M][K] * B[N][K]^T (3-term compensated) -------------
__global__ __launch_bounds__(256) void k_gemm(const u16* __restrict__ Ah, const u16* __restrict__ Al,
    const u16* __restrict__ Bh, const u16* __restrict__ Bl, float* __restrict__ C,
    int M, int N, int K){
  __shared__ u16 As[2][128][72];
  __shared__ u16 Bs[2][64][72];
  int t = threadIdx.x;
  int n0 = blockIdx.x*64, m0 = blockIdx.y*128;
  int w = t>>6, lane = t&63, lg = lane>>4, lr = lane&15;
  int iw = w&1, jw = w>>1;
  f32x4 acc[4][2] = {};
  for (int k0=0; k0<K; k0+=64){
    __syncthreads();
    #pragma unroll
    for (int it=0; it<4; ++it){
      int id = it*256+t; int row=id>>3, c8=id&7;
      *(uint4*)&As[0][row][c8*8] = *(const uint4*)(Ah + (size_t)(m0+row)*K + k0 + c8*8);
      *(uint4*)&As[1][row][c8*8] = *(const uint4*)(Al + (size_t)(m0+row)*K + k0 + c8*8);
    }
    #pragma unroll
    for (int it=0; it<2; ++it){
      int id = it*256+t; int row=id>>3, c8=id&7;
      *(uint4*)&Bs[0][row][c8*8] = *(const uint4*)(Bh + (size_t)(n0+row)*K + k0 + c8*8);
      *(uint4*)&Bs[1][row][c8*8] = *(const uint4*)(Bl + (size_t)(n0+row)*K + k0 + c8*8);
    }
    __syncthreads();
    #pragma unroll
    for (int ks=0; ks<2; ++ks){
      int kk = ks*32 + lg*8;
      s16x8 ah[4], al[4], bh[2], bl[2];
      #pragma unroll
      for (int m=0;m<4;++m){
        int r = iw*64 + m*16 + lr;
        ah[m] = *(const s16x8*)&As[0][r][kk];
        al[m] = *(const s16x8*)&As[1][r][kk];
      }
      #pragma unroll
      for (int nn=0;nn<2;++nn){
        int r = jw*32 + nn*16 + lr;
        bh[nn] = *(const s16x8*)&Bs[0][r][kk];
        bl[nn] = *(const s16x8*)&Bs[1][r][kk];
      }
      #pragma unroll
      for (int m=0;m<4;++m)
        #pragma unroll
        for(int nn=0;nn<2;++nn){
          acc[m][nn] = mfma16(ah[m], bh[nn], acc[m][nn]);
          acc[m][nn] = mfma16(ah[m], bl[nn], acc[m][nn]);
          acc[m][nn] = mfma16(al[m], bh[nn], acc[m][nn]);
        }
    }
  }
  #pragma unroll
  for (int m=0;m<4;++m)
    #pragma unroll
    for(int nn=0;nn<2;++nn)
      #pragma unroll
      for(int r=0;r<4;++r){
        int row = m0 + iw*64 + m*16 + lg*4 + r;
        int col = n0 + jw*32 + nn*16 + lr;
        C[(size_t)row*N + col] = acc[m][nn][r];
      }
}

// ------------- rmsnorm + rope + split/transposed layouts -------------
__device__ __forceinline__ float blocksum128(float v, float* red, int t){
  #pragma unroll
  for (int m=32; m>=1; m>>=1) v += __shfl_xor(v, m, 64);
  __syncthreads();
  if ((t&63)==0) red[t>>6] = v;
  __syncthreads();
  return red[0] + red[1];
}

__global__ __launch_bounds__(128) void k_normrope(const float* __restrict__ qkv,
   const float* __restrict__ rot, const float* __restrict__ qw, const float* __restrict__ kw,
   const float* __restrict__ vw, u16* __restrict__ Qh, u16* __restrict__ Ql,
   u16* __restrict__ Kh, u16* __restrict__ Kl, u16* __restrict__ Vt){
  __shared__ float buf[128];
  __shared__ float red[2];
  int n = blockIdx.x, t = threadIdx.x;
  const float* row = qkv + (size_t)n*1344;
  float pos = rot[(size_t)n*128 + t];
  float cs = cosf(pos), sn = sinf(pos);
  float qwt = qw[t], kwt = kw[t];
  #pragma unroll 1
  for (int h=0; h<8; ++h){
    float v = row[h*128 + t];
    float ss = blocksum128(v*v, red, t);
    float rr = rsqrtf(ss*(1.0f/128.0f) + 1.1920929e-07f);
    float qn = v*rr*qwt*0.125f;
    __syncthreads();
    buf[t] = qn;
    __syncthreads();
    float partner = (t<64) ? -buf[t+64] : buf[t-64];
    float o = qn*cs + partner*sn;
    u16 hh = f2bf(o);
    size_t oi = ((size_t)h*2048 + n)*128 + t;
    Qh[oi] = hh; Ql[oi] = f2bf(o - bf2f(hh));
  }
  {
    float v = row[1024 + t];
    float ss = blocksum128(v*v, red, t);
    float rr = rsqrtf(ss*(1.0f/128.0f) + 1.1920929e-07f);
    float kn = v*rr*kwt;
    __syncthreads();
    buf[t] = kn;
    __syncthreads();
    float partner = (t<64) ? -buf[t+64] : buf[t-64];
    float o = kn*cs + partner*sn;
    u16 hh = f2bf(o);
    size_t oi = (size_t)n*128 + t;
    Kh[oi] = hh; Kl[oi] = f2bf(o - bf2f(hh));
  }
  {
    float v0 = row[1152 + t];
    float v1 = (t<64) ? row[1280 + t] : 0.0f;
    float ss = blocksum128(v0*v0 + v1*v1, red, t);
    float rr = rsqrtf(ss*(1.0f/192.0f) + 1.1920929e-07f);
    Vt[(size_t)t*2048 + n] = f2bf(v0*rr*vw[t]);
    if (t < 64) Vt[(size_t)(128+t)*2048 + n] = f2bf(v1*rr*vw[128+t]);
  }
}

// ------------- pairwise -> attention bias: bias[h][i][j] -------------
__global__ __launch_bounds__(256) void k_bias(const float* __restrict__ pw, const float* __restrict__ rv,
  const float* __restrict__ gamma, const float* __restrict__ beta, const float* __restrict__ Wb,
  float* __restrict__ bias){
  int t = threadIdx.x;
  int g = t & 31, sub = t >> 5;
  size_t pair = (size_t)blockIdx.x*8 + sub;
  int c = g*4;
  const float4 x4  = *(const float4*)(pw + pair*128 + c);
  const float4 rv4 = *(const float4*)(rv + c);
  const float4 g4  = *(const float4*)(gamma + c);
  const float4 b4  = *(const float4*)(beta + c);
  float xs[4] = {x4.x, x4.y, x4.z, x4.w};
  float rvs[4] = {rv4.x, rv4.y, rv4.z, rv4.w};
  float gs[4] = {g4.x, g4.y, g4.z, g4.w};
  float bs[4] = {b4.x, b4.y, b4.z, b4.w};
  float p[8] = {0,0,0,0,0,0,0,0};
  #pragma unroll
  for (int kk=0; kk<4; ++kk){
    float xv = xs[kk] * (11.313708498984761f * rsqrtf(fmaxf(rvs[kk], 1e-5f))) * (gs[kk] + 1.0f) + bs[kk];
    float ge = 0.5f * xv * (1.0f + erff(xv * 0.7071067811865476f));
    #pragma unroll
    for (int hh=0; hh<8; ++hh) p[hh] += ge * Wb[(c+kk)*8 + hh];
  }
  #pragma unroll
  for (int m=1; m<32; m<<=1){
    #pragma unroll
    for (int hh=0; hh<8; ++hh) p[hh] += __shfl_xor(p[hh], m, 64);
  }
  if (g < 8) bias[(size_t)g*(512*512) + pair] = p[g];
}

// ------------- fused attention v2: no K/V LDS staging, key-dim partitioned, atomic partials -------------
__global__ __launch_bounds__(256,4) void k_attn2(const u16* __restrict__ Qh, const u16* __restrict__ Ql,
  const u16* __restrict__ Kh, const u16* __restrict__ Kl, const u16* __restrict__ Vt,
  const float* __restrict__ bias, float* __restrict__ Oacc, float* __restrict__ Sacc){
  __shared__ u16 PS[2][32][40];
  int t = threadIdx.x;
  int h = blockIdx.y;
  int q0 = blockIdx.x * 32;
  int jbase = blockIdx.z * 512;
  int w = t>>6, lane = t&63, lg = lane>>4, lr = lane&15;
  int iw = w&1, jw = w>>1;
  s16x8 qfh[4], qfl[4];
  {
    int row = q0 + iw*16 + lr;
    const u16* qb  = Qh + ((size_t)h*2048 + row)*128;
    const u16* qb2 = Ql + ((size_t)h*2048 + row)*128;
    #pragma unroll
    for (int ks=0; ks<4; ++ks){
      qfh[ks] = *(const s16x8*)(qb  + ks*32 + lg*8);
      qfl[ks] = *(const s16x8*)(qb2 + ks*32 + lg*8);
    }
  }
  f32x4 accO[6] = {};
  float psum[4] = {0,0,0,0};
  const float* biasRow = bias + (size_t)h*512*512 + (size_t)((q0+iw*16+lg*4)>>2)*512;
  #pragma unroll 2
  for (int jt=0; jt<16; ++jt){
    int j0 = jbase + jt*32;
    f32x4 accS = {0.f,0.f,0.f,0.f};
    const u16* kh = Kh + (size_t)(j0 + jw*16 + lr)*128 + lg*8;
    const u16* kl = Kl + (size_t)(j0 + jw*16 + lr)*128 + lg*8;
    #pragma unroll
    for (int ks=0; ks<4; ++ks){
      s16x8 kbh = *(const s16x8*)(kh + ks*32);
      s16x8 kbl = *(const s16x8*)(kl + ks*32);
      accS = mfma16(qfh[ks], kbh, accS);
      accS = mfma16(qfh[ks], kbl, accS);
      accS = mfma16(qfl[ks], kbh, accS);
    }
    float bsv = biasRow[(j0 + jw*16 + lr)>>2];
    int cur = jt & 1;
    // p = exp(5*tanh(s/5)) = e^5 * exp(-10/(e^{0.4 s}+1))
    #pragma unroll
    for (int r=0; r<4; ++r){
      float s = accS[r] + bsv;
      float te = __expf(0.4f*s);
      float ri; asm("v_rcp_f32 %0, %1" : "=v"(ri) : "v"(te + 1.0f));
      float p = 148.4131591f * __expf(-10.0f*ri);
      psum[r] += p;
      PS[cur][iw*16+lg*4+r][jw*16+lr] = f2bf(p);
    }
    __syncthreads();
    s16x8 pa = *(const s16x8*)&PS[cur][iw*16+lr][lg*8];
    #pragma unroll
    for (int df=0; df<6; ++df){
      s16x8 vb = *(const s16x8*)(Vt + (size_t)(jw*96+df*16+lr)*2048 + j0 + lg*8);
      accO[df] = mfma16(pa, vb, accO[df]);
    }
  }
  #pragma unroll
  for (int m=1; m<16; m<<=1){
    #pragma unroll
    for (int r=0; r<4; ++r) psum[r] += __shfl_xor(psum[r], m, 64);
  }
  if (lr == 0){
    #pragma unroll
    for (int r=0; r<4; ++r)
      atomicAdd(&Sacc[h*2048 + q0 + iw*16 + lg*4 + r], psum[r]);
  }
  #pragma unroll
  for (int df=0; df<6; ++df)
    #pragma unroll
    for (int r=0; r<4; ++r)
      atomicAdd(&Oacc[((size_t)h*2048 + q0 + iw*16 + lg*4 + r)*192 + jw*96 + df*16 + lr], accO[df][r]);
}

// ------------- normalize partials, relayout to [q][h*192+d], bf16 hi/lo split -------------
__global__ __launch_bounds__(256) void k_attnred(const float* __restrict__ Oacc,
    const float* __restrict__ Sacc, u16* __restrict__ Oh, u16* __restrict__ Ol){
  int id = blockIdx.x*256 + threadIdx.x;   // 8*2048*48 threads, 4 d each
  float4 a = ((const float4*)Oacc)[id];
  int hq = id / 48;
  int d4 = id - hq*48;
  float inv = 1.0f / Sacc[hq];
  int hh = hq >> 11, q = hq & 2047;
  size_t o = (size_t)q*1536 + hh*192 + d4*4;
  float vv[4] = {a.x, a.y, a.z, a.w};
  u16 rh[4], rl[4];
  #pragma unroll
  for (int j=0; j<4; ++j){
    float v = vv[j]*inv;
    rh[j] = f2bf(v);
    rl[j] = f2bf(v - bf2f(rh[j]));
  }
  *(ushort4*)(Oh+o) = make_ushort4(rh[0],rh[1],rh[2],rh[3]);
  *(ushort4*)(Ol+o) = make_ushort4(rl[0],rl[1],rl[2],rl[3]);
}

extern "C" void kernel_launch(void* const* d_in, const int* in_sizes, int n_in,
                              void* d_out, int out_size, void* d_ws, size_t ws_size,
                              hipStream_t stream){
  (void)in_sizes; (void)n_in; (void)out_size; (void)ws_size;
  const float* x   = (const float*)d_in[0];
  const float* pwi = (const float*)d_in[1];
  const float* rot = (const float*)d_in[2];
  const float* Wq  = (const float*)d_in[3];
  const float* qw  = (const float*)d_in[4];
  const float* kw  = (const float*)d_in[5];
  const float* vw  = (const float*)d_in[6];
  const float* gm  = (const float*)d_in[7];
  const float* bt  = (const float*)d_in[8];
  const float* rvv = (const float*)d_in[9];
  const float* Wb  = (const float*)d_in[10];
  const float* Wo  = (const float*)d_in[11];
  float* out = (float*)d_out;
  char* ws = (char*)d_ws;
  size_t off = 0;
  auto alloc = [&](size_t bytes)->char*{
    char* p = ws + off; off = (off + bytes + 255) & ~(size_t)255; return p;
  };
  u16* xh  = (u16*)alloc(2048ull*1024*2);
  u16* xl  = (u16*)alloc(2048ull*1024*2);
  u16* Wqh = (u16*)alloc(1344ull*1024*2);
  u16* Wql = (u16*)alloc(1344ull*1024*2);
  u16* Woh = (u16*)alloc(1024ull*1536*2);
  u16* Wol = (u16*)alloc(1024ull*1536*2);
  float* qkv = (float*)alloc(2048ull*1344*4);
  u16* Qhb = (u16*)alloc(8ull*2048*128*2);
  u16* Qlb = (u16*)alloc(8ull*2048*128*2);
  u16* Khb = (u16*)alloc(2048ull*128*2);
  u16* Klb = (u16*)alloc(2048ull*128*2);
  u16* Vtb = (u16*)alloc(192ull*2048*2);
  float* bias = (float*)alloc(8ull*512*512*4);
  u16* Ohb = (u16*)alloc(2048ull*1536*2);
  u16* Olb = (u16*)alloc(2048ull*1536*2);
  // Oacc/Sacc alias the [xh, xl, Wqh, Wql] region (13.9 MB), which is dead
  // after the first k_gemm. Oacc+Sacc = 12.65 MB. Zeroed after that gemm.
  float* Oacc = (float*)ws;                               // [8][2048][192] f32
  float* Sacc = (float*)(ws + 8ull*2048*192*4);           // [8][2048] f32

  k_split<<<2048, 256, 0, stream>>>(x, xh, xl, 524288);
  k_tsplit<<<dim3(1344/32, 1024/32), 256, 0, stream>>>(Wq, Wqh, Wql, 1024, 1344);
  k_tsplit<<<dim3(1024/32, 1536/32), 256, 0, stream>>>(Wo, Woh, Wol, 1536, 1024);
  k_gemm<<<dim3(1344/64, 2048/128), 256, 0, stream>>>(xh, xl, Wqh, Wql, qkv, 2048, 1344, 1024);
  hipMemsetAsync(Oacc, 0, (8ull*2048*192 + 8ull*2048)*4, stream);
  k_normrope<<<2048, 128, 0, stream>>>(qkv, rot, qw, kw, vw, Qhb, Qlb, Khb, Klb, Vtb);
  k_bias<<<512*512/8, 256, 0, stream>>>(pwi, rvv, gm, bt, Wb, bias);
  k_attn2<<<dim3(64, 8, 4), 256, 0, stream>>>(Qhb, Qlb, Khb, Klb, Vtb, bias, Oacc, Sacc);
  k_attnred<<<3072, 256, 0, stream>>>(Oacc, Sacc, Ohb, Olb);
  k_gemm<<<dim3(1024/64, 2048/128), 256, 0, stream>>>(Ohb, Olb, Woh, Wol, out, 2048, 1024, 1536);
}

// Round 4
// 363.738 us; speedup vs baseline: 1.2540x; 1.2540x over previous
//
#include <hip/hip_runtime.h>
#include <math.h>

typedef unsigned short u16;
typedef __attribute__((ext_vector_type(4))) float f32x4;
typedef __attribute__((ext_vector_type(8))) short s16x8;

__device__ __forceinline__ u16 f2bf(float f){
  unsigned u = __builtin_bit_cast(unsigned, f);
  u += 0x7fffu + ((u >> 16) & 1u);
  return (u16)(u >> 16);
}
__device__ __forceinline__ float bf2f(u16 h){
  unsigned u = ((unsigned)h) << 16;
  return __builtin_bit_cast(float, u);
}
__device__ __forceinline__ f32x4 mfma16(s16x8 a, s16x8 b, f32x4 c){
  return __builtin_amdgcn_mfma_f32_16x16x32_bf16(a, b, c, 0, 0, 0);
}

// ---------------- split x -> bf16 hi/lo ----------------
__global__ __launch_bounds__(256) void k_split(const float* __restrict__ x,
    u16* __restrict__ xh, u16* __restrict__ xl, int n4){
  int id = blockIdx.x*256 + threadIdx.x;
  if (id >= n4) return;
  float4 v = ((const float4*)x)[id];
  float vv[4] = {v.x, v.y, v.z, v.w};
  u16 hh[4], ll[4];
  #pragma unroll
  for (int i=0;i<4;++i){ hh[i] = f2bf(vv[i]); ll[i] = f2bf(vv[i] - bf2f(hh[i])); }
  ((ushort4*)xh)[id] = make_ushort4(hh[0],hh[1],hh[2],hh[3]);
  ((ushort4*)xl)[id] = make_ushort4(ll[0],ll[1],ll[2],ll[3]);
}

// ------------- transpose + split: in[R][C] f32 -> out[C][R] bf16 hi/lo -------------
__global__ __launch_bounds__(256) void k_tsplit(const float* __restrict__ in,
    u16* __restrict__ oh, u16* __restrict__ ol, int R, int C){
  __shared__ float tile[32][33];
  int tx = threadIdx.x & 31, ty = threadIdx.x >> 5;
  int c0 = blockIdx.x*32, r0 = blockIdx.y*32;
  #pragma unroll
  for (int rr=0; rr<4; ++rr){
    int row = ty*4 + rr;
    tile[row][tx] = in[(size_t)(r0+row)*C + (c0+tx)];
  }
  __syncthreads();
  #pragma unroll
  for (int rr=0; rr<4; ++rr){
    int row = ty*4 + rr;
    float v = tile[tx][row];
    size_t o = (size_t)(c0+row)*R + (r0+tx);
    u16 hh = f2bf(v);
    oh[o] = hh; ol[o] = f2bf(v - bf2f(hh));
  }
}

// ------------- split-bf16 GEMM: C[M][N] = A[M][K] * B[N][K]^T (3-term compensated) -------------
__global__ __launch_bounds__(256) void k_gemm(const u16* __restrict__ Ah, const u16* __restrict__ Al,
    const u16* __restrict__ Bh, const u16* __restrict__ Bl, float* __restrict__ C,
    int M, int N, int K){
  __shared__ u16 As[2][128][72];
  __shared__ u16 Bs[2][64][72];
  int t = threadIdx.x;
  int n0 = blockIdx.x*64, m0 = blockIdx.y*128;
  int w = t>>6, lane = t&63, lg = lane>>4, lr = lane&15;
  int iw = w&1, jw = w>>1;
  f32x4 acc[4][2] = {};
  for (int k0=0; k0<K; k0+=64){
    __syncthreads();
    #pragma unroll
    for (int it=0; it<4; ++it){
      int id = it*256+t; int row=id>>3, c8=id&7;
      *(uint4*)&As[0][row][c8*8] = *(const uint4*)(Ah + (size_t)(m0+row)*K + k0 + c8*8);
      *(uint4*)&As[1][row][c8*8] = *(const uint4*)(Al + (size_t)(m0+row)*K + k0 + c8*8);
    }
    #pragma unroll
    for (int it=0; it<2; ++it){
      int id = it*256+t; int row=id>>3, c8=id&7;
      *(uint4*)&Bs[0][row][c8*8] = *(const uint4*)(Bh + (size_t)(n0+row)*K + k0 + c8*8);
      *(uint4*)&Bs[1][row][c8*8] = *(const uint4*)(Bl + (size_t)(n0+row)*K + k0 + c8*8);
    }
    __syncthreads();
    #pragma unroll
    for (int ks=0; ks<2; ++ks){
      int kk = ks*32 + lg*8;
      s16x8 ah[4], al[4], bh[2], bl[2];
      #pragma unroll
      for (int m=0;m<4;++m){
        int r = iw*64 + m*16 + lr;
        ah[m] = *(const s16x8*)&As[0][r][kk];
        al[m] = *(const s16x8*)&As[1][r][kk];
      }
      #pragma unroll
      for (int nn=0;nn<2;++nn){
        int r = jw*32 + nn*16 + lr;
        bh[nn] = *(const s16x8*)&Bs[0][r][kk];
        bl[nn] = *(const s16x8*)&Bs[1][r][kk];
      }
      #pragma unroll
      for (int m=0;m<4;++m)
        #pragma unroll
        for(int nn=0;nn<2;++nn){
          acc[m][nn] = mfma16(ah[m], bh[nn], acc[m][nn]);
          acc[m][nn] = mfma16(ah[m], bl[nn], acc[m][nn]);
          acc[m][nn] = mfma16(al[m], bh[nn], acc[m][nn]);
        }
    }
  }
  #pragma unroll
  for (int m=0;m<4;++m)
    #pragma unroll
    for(int nn=0;nn<2;++nn)
      #pragma unroll
      for(int r=0;r<4;++r){
        int row = m0 + iw*64 + m*16 + lg*4 + r;
        int col = n0 + jw*32 + nn*16 + lr;
        C[(size_t)row*N + col] = acc[m][nn][r];
      }
}

// ------------- rmsnorm + rope + split/transposed layouts -------------
__device__ __forceinline__ float blocksum128(float v, float* red, int t){
  #pragma unroll
  for (int m=32; m>=1; m>>=1) v += __shfl_xor(v, m, 64);
  __syncthreads();
  if ((t&63)==0) red[t>>6] = v;
  __syncthreads();
  return red[0] + red[1];
}

__global__ __launch_bounds__(128) void k_normrope(const float* __restrict__ qkv,
   const float* __restrict__ rot, const float* __restrict__ qw, const float* __restrict__ kw,
   const float* __restrict__ vw, u16* __restrict__ Qh, u16* __restrict__ Ql,
   u16* __restrict__ Kh, u16* __restrict__ Kl, u16* __restrict__ Vt){
  __shared__ float buf[128];
  __shared__ float red[2];
  int n = blockIdx.x, t = threadIdx.x;
  const float* row = qkv + (size_t)n*1344;
  float pos = rot[(size_t)n*128 + t];
  float cs = cosf(pos), sn = sinf(pos);
  float qwt = qw[t], kwt = kw[t];
  #pragma unroll 1
  for (int h=0; h<8; ++h){
    float v = row[h*128 + t];
    float ss = blocksum128(v*v, red, t);
    float rr = rsqrtf(ss*(1.0f/128.0f) + 1.1920929e-07f);
    float qn = v*rr*qwt*0.125f;
    __syncthreads();
    buf[t] = qn;
    __syncthreads();
    float partner = (t<64) ? -buf[t+64] : buf[t-64];
    float o = qn*cs + partner*sn;
    u16 hh = f2bf(o);
    size_t oi = ((size_t)h*2048 + n)*128 + t;
    Qh[oi] = hh; Ql[oi] = f2bf(o - bf2f(hh));
  }
  {
    float v = row[1024 + t];
    float ss = blocksum128(v*v, red, t);
    float rr = rsqrtf(ss*(1.0f/128.0f) + 1.1920929e-07f);
    float kn = v*rr*kwt;
    __syncthreads();
    buf[t] = kn;
    __syncthreads();
    float partner = (t<64) ? -buf[t+64] : buf[t-64];
    float o = kn*cs + partner*sn;
    u16 hh = f2bf(o);
    size_t oi = (size_t)n*128 + t;
    Kh[oi] = hh; Kl[oi] = f2bf(o - bf2f(hh));
  }
  {
    float v0 = row[1152 + t];
    float v1 = (t<64) ? row[1280 + t] : 0.0f;
    float ss = blocksum128(v0*v0 + v1*v1, red, t);
    float rr = rsqrtf(ss*(1.0f/192.0f) + 1.1920929e-07f);
    Vt[(size_t)t*2048 + n] = f2bf(v0*rr*vw[t]);
    if (t < 64) Vt[(size_t)(128+t)*2048 + n] = f2bf(v1*rr*vw[128+t]);
  }
}

// ------------- pairwise -> attention bias: bias[h][i][j] -------------
__global__ __launch_bounds__(256) void k_bias(const float* __restrict__ pw, const float* __restrict__ rv,
  const float* __restrict__ gamma, const float* __restrict__ beta, const float* __restrict__ Wb,
  float* __restrict__ bias){
  int t = threadIdx.x;
  int g = t & 31, sub = t >> 5;
  size_t pair = (size_t)blockIdx.x*8 + sub;
  int c = g*4;
  const float4 x4  = *(const float4*)(pw + pair*128 + c);
  const float4 rv4 = *(const float4*)(rv + c);
  const float4 g4  = *(const float4*)(gamma + c);
  const float4 b4  = *(const float4*)(beta + c);
  float xs[4] = {x4.x, x4.y, x4.z, x4.w};
  float rvs[4] = {rv4.x, rv4.y, rv4.z, rv4.w};
  float gs[4] = {g4.x, g4.y, g4.z, g4.w};
  float bs[4] = {b4.x, b4.y, b4.z, b4.w};
  float p[8] = {0,0,0,0,0,0,0,0};
  #pragma unroll
  for (int kk=0; kk<4; ++kk){
    float xv = xs[kk] * (11.313708498984761f * rsqrtf(fmaxf(rvs[kk], 1e-5f))) * (gs[kk] + 1.0f) + bs[kk];
    float ge = 0.5f * xv * (1.0f + erff(xv * 0.7071067811865476f));
    #pragma unroll
    for (int hh=0; hh<8; ++hh) p[hh] += ge * Wb[(c+kk)*8 + hh];
  }
  #pragma unroll
  for (int m=1; m<32; m<<=1){
    #pragma unroll
    for (int hh=0; hh<8; ++hh) p[hh] += __shfl_xor(p[hh], m, 64);
  }
  if (g < 8) bias[(size_t)g*(512*512) + pair] = p[g];
}

// ------------- fused attention v4: GQA — 4 heads/block share staged K/V -------------
// Built only from round-1/2-verified fragments: standard QK^T orientation,
// padded LDS staging, per-wave P buffer (no cross-wave use -> no P barrier),
// z=4 key partition + atomic partials. T14 split: next tile's global loads
// issued right after staging barriers, consumed next iteration.
__global__ __launch_bounds__(256,2) void k_attn4(const u16* __restrict__ Qh, const u16* __restrict__ Ql,
  const u16* __restrict__ Kh, const u16* __restrict__ Kl, const u16* __restrict__ Vt,
  const float* __restrict__ bias, float* __restrict__ Oacc, float* __restrict__ Sacc){
  __shared__ u16 KhS[32][136];
  __shared__ u16 KlS[32][136];
  __shared__ u16 VtS[192][40];
  __shared__ u16 PS[4][32][40];
  int t = threadIdx.x;
  int w = t>>6, lane = t&63, lg = lane>>4, lr = lane&15;
  int q0 = blockIdx.x*32;
  int h = blockIdx.y*4 + w;            // one head per wave
  int jbase = blockIdx.z*512;
  // Q fragments (hi+lo), 3-term compensated QK^T
  s16x8 qfh[2][4], qfl[2][4];
  #pragma unroll
  for (int qi=0; qi<2; ++qi){
    const u16* qb  = Qh + ((size_t)h*2048 + q0 + qi*16 + lr)*128 + lg*8;
    const u16* qb2 = Ql + ((size_t)h*2048 + q0 + qi*16 + lr)*128 + lg*8;
    #pragma unroll
    for (int ks=0; ks<4; ++ks){
      qfh[qi][ks] = *(const s16x8*)(qb  + ks*32);
      qfl[qi][ks] = *(const s16x8*)(qb2 + ks*32);
    }
  }
  // cooperative staging addresses (same verified patterns as round 1)
  int rK[2], cK[2], rV[3], cV[3];
  #pragma unroll
  for (int i=0;i<2;++i){ int id=i*256+t; rK[i]=id>>4; cK[i]=(id&15)*8; }
  #pragma unroll
  for (int i=0;i<3;++i){ int id=i*256+t; rV[i]=id>>2; cV[i]=(id&3)*8; }
  uint4 sKh[2], sKl[2], sV[3];
  auto issue = [&](int j0){
    #pragma unroll
    for (int i=0;i<2;++i){
      sKh[i] = *(const uint4*)(Kh + (size_t)(j0+rK[i])*128 + cK[i]);
      sKl[i] = *(const uint4*)(Kl + (size_t)(j0+rK[i])*128 + cK[i]);
    }
    #pragma unroll
    for (int i=0;i<3;++i)
      sV[i] = *(const uint4*)(Vt + (size_t)rV[i]*2048 + j0 + cV[i]);
  };
  issue(jbase);
  f32x4 accO[2][12] = {};
  float psum[2][4] = {};
  const float* biasH = bias + (size_t)h*262144;
  int bRow = (q0>>2) + lg;             // + qi*4 ; constant over r
  for (int jt=0; jt<16; ++jt){
    int j0 = jbase + jt*32;
    __syncthreads();                   // all waves done reading prev K/V
    #pragma unroll
    for (int i=0;i<2;++i){
      *(uint4*)&KhS[rK[i]][cK[i]] = sKh[i];
      *(uint4*)&KlS[rK[i]][cK[i]] = sKl[i];
    }
    #pragma unroll
    for (int i=0;i<3;++i) *(uint4*)&VtS[rV[i]][cV[i]] = sV[i];
    __syncthreads();                   // staged tile visible
    if (jt < 15) issue(j0 + 32);       // prefetch next tile into regs
    // QK^T : A=Q rows, B=K rows (verified v1 orientation)
    f32x4 accS[2][2] = {};
    #pragma unroll
    for (int ks=0; ks<4; ++ks){
      int kk = ks*32 + lg*8;
      s16x8 kbh[2], kbl[2];
      #pragma unroll
      for (int kj=0; kj<2; ++kj){
        kbh[kj] = *(const s16x8*)&KhS[kj*16+lr][kk];
        kbl[kj] = *(const s16x8*)&KlS[kj*16+lr][kk];
      }
      #pragma unroll
      for (int qi=0; qi<2; ++qi)
        #pragma unroll
        for (int kj=0; kj<2; ++kj){
          accS[qi][kj] = mfma16(qfh[qi][ks], kbh[kj], accS[qi][kj]);
          accS[qi][kj] = mfma16(qfh[qi][ks], kbl[kj], accS[qi][kj]);
          accS[qi][kj] = mfma16(qfl[qi][ks], kbh[kj], accS[qi][kj]);
        }
    }
    // bias + softcap exp + P write (per-wave buffer, no barrier)
    #pragma unroll
    for (int qi=0; qi<2; ++qi)
      #pragma unroll
      for (int kj=0; kj<2; ++kj){
        float bv = biasH[(size_t)(bRow + qi*4)*512 + ((j0 + kj*16)>>2) + (lr>>2)];
        #pragma unroll
        for (int r=0; r<4; ++r){
          float s = accS[qi][kj][r] + bv;
          // p = exp(5*tanh(s/5)) = e^5 * exp(-10/(e^{0.4 s}+1))
          float te = __expf(0.4f*s);
          float ri; asm("v_rcp_f32 %0, %1" : "=v"(ri) : "v"(te + 1.0f));
          float p = 148.4131591f * __expf(-10.0f*ri);
          psum[qi][r] += p;
          PS[w][qi*16+lg*4+r][kj*16+lr] = f2bf(p);
        }
      }
    // PV : A=P (K=32 keys), B=V^T tile (verified v1 orientation)
    #pragma unroll
    for (int qi=0; qi<2; ++qi){
      s16x8 pa = *(const s16x8*)&PS[w][qi*16+lr][lg*8];
      #pragma unroll
      for (int df=0; df<12; ++df){
        s16x8 vb = *(const s16x8*)&VtS[df*16+lr][lg*8];
        accO[qi][df] = mfma16(pa, vb, accO[qi][df]);
      }
    }
  }
  // row-sum partials
  #pragma unroll
  for (int qi=0; qi<2; ++qi){
    #pragma unroll
    for (int m=1; m<16; m<<=1)
      #pragma unroll
      for (int r=0; r<4; ++r) psum[qi][r] += __shfl_xor(psum[qi][r], m, 64);
    if (lr == 0)
      #pragma unroll
      for (int r=0; r<4; ++r)
        atomicAdd(&Sacc[h*2048 + q0 + qi*16 + lg*4 + r], psum[qi][r]);
  }
  // output partials
  #pragma unroll
  for (int qi=0; qi<2; ++qi)
    #pragma unroll
    for (int df=0; df<12; ++df)
      #pragma unroll
      for (int r=0; r<4; ++r)
        atomicAdd(&Oacc[((size_t)h*2048 + q0 + qi*16 + lg*4 + r)*192 + df*16 + lr], accO[qi][df][r]);
}

// ------------- normalize partials, relayout to [q][h*192+d], bf16 hi/lo split -------------
__global__ __launch_bounds__(256) void k_attnred(const float* __restrict__ Oacc,
    const float* __restrict__ Sacc, u16* __restrict__ Oh, u16* __restrict__ Ol){
  int id = blockIdx.x*256 + threadIdx.x;   // 8*2048*48 threads, 4 d each
  float4 a = ((const float4*)Oacc)[id];
  int hq = id / 48;
  int d4 = id - hq*48;
  float inv = 1.0f / Sacc[hq];
  int hh = hq >> 11, q = hq & 2047;
  size_t o = (size_t)q*1536 + hh*192 + d4*4;
  float vv[4] = {a.x, a.y, a.z, a.w};
  u16 rh[4], rl[4];
  #pragma unroll
  for (int j=0; j<4; ++j){
    float v = vv[j]*inv;
    rh[j] = f2bf(v);
    rl[j] = f2bf(v - bf2f(rh[j]));
  }
  *(ushort4*)(Oh+o) = make_ushort4(rh[0],rh[1],rh[2],rh[3]);
  *(ushort4*)(Ol+o) = make_ushort4(rl[0],rl[1],rl[2],rl[3]);
}

extern "C" void kernel_launch(void* const* d_in, const int* in_sizes, int n_in,
                              void* d_out, int out_size, void* d_ws, size_t ws_size,
                              hipStream_t stream){
  (void)in_sizes; (void)n_in; (void)out_size; (void)ws_size;
  const float* x   = (const float*)d_in[0];
  const float* pwi = (const float*)d_in[1];
  const float* rot = (const float*)d_in[2];
  const float* Wq  = (const float*)d_in[3];
  const float* qw  = (const float*)d_in[4];
  const float* kw  = (const float*)d_in[5];
  const float* vw  = (const float*)d_in[6];
  const float* gm  = (const float*)d_in[7];
  const float* bt  = (const float*)d_in[8];
  const float* rvv = (const float*)d_in[9];
  const float* Wb  = (const float*)d_in[10];
  const float* Wo  = (const float*)d_in[11];
  float* out = (float*)d_out;
  char* ws = (char*)d_ws;
  size_t off = 0;
  auto alloc = [&](size_t bytes)->char*{
    char* p = ws + off; off = (off + bytes + 255) & ~(size_t)255; return p;
  };
  u16* xh  = (u16*)alloc(2048ull*1024*2);
  u16* xl  = (u16*)alloc(2048ull*1024*2);
  u16* Wqh = (u16*)alloc(1344ull*1024*2);
  u16* Wql = (u16*)alloc(1344ull*1024*2);
  u16* Woh = (u16*)alloc(1024ull*1536*2);
  u16* Wol = (u16*)alloc(1024ull*1536*2);
  float* qkv = (float*)alloc(2048ull*1344*4);
  u16* Qhb = (u16*)alloc(8ull*2048*128*2);
  u16* Qlb = (u16*)alloc(8ull*2048*128*2);
  u16* Khb = (u16*)alloc(2048ull*128*2);
  u16* Klb = (u16*)alloc(2048ull*128*2);
  u16* Vtb = (u16*)alloc(192ull*2048*2);
  float* bias = (float*)alloc(8ull*512*512*4);
  u16* Ohb = (u16*)alloc(2048ull*1536*2);
  u16* Olb = (u16*)alloc(2048ull*1536*2);
  // Oacc/Sacc alias the [xh, xl, Wqh, Wql] region (13.9 MB), dead after gemm1.
  float* Oacc = (float*)ws;                               // [8][2048][192] f32
  float* Sacc = (float*)(ws + 8ull*2048*192*4);           // [8][2048] f32

  k_split<<<2048, 256, 0, stream>>>(x, xh, xl, 524288);
  k_tsplit<<<dim3(1344/32, 1024/32), 256, 0, stream>>>(Wq, Wqh, Wql, 1024, 1344);
  k_tsplit<<<dim3(1024/32, 1536/32), 256, 0, stream>>>(Wo, Woh, Wol, 1536, 1024);
  k_gemm<<<dim3(1344/64, 2048/128), 256, 0, stream>>>(xh, xl, Wqh, Wql, qkv, 2048, 1344, 1024);
  hipMemsetAsync(Oacc, 0, (8ull*2048*192 + 8ull*2048)*4, stream);
  k_normrope<<<2048, 128, 0, stream>>>(qkv, rot, qw, kw, vw, Qhb, Qlb, Khb, Klb, Vtb);
  k_bias<<<512*512/8, 256, 0, stream>>>(pwi, rvv, gm, bt, Wb, bias);
  k_attn4<<<dim3(64, 2, 4), 256, 0, stream>>>(Qhb, Qlb, Khb, Klb, Vtb, bias, Oacc, Sacc);
  k_attnred<<<3072, 256, 0, stream>>>(Oacc, Sacc, Ohb, Olb);
  k_gemm<<<dim3(1024/64, 2048/128), 256, 0, stream>>>(Ohb, Olb, Woh, Wol, out, 2048, 1024, 1536);
}

// Round 5
// 272.829 us; speedup vs baseline: 1.6718x; 1.3332x over previous
//
#include <hip/hip_runtime.h>
#include <math.h>

typedef unsigned short u16;
typedef __attribute__((ext_vector_type(4))) float f32x4;
typedef __attribute__((ext_vector_type(8))) short s16x8;

__device__ __forceinline__ u16 f2bf(float f){
  unsigned u = __builtin_bit_cast(unsigned, f);
  u += 0x7fffu + ((u >> 16) & 1u);
  return (u16)(u >> 16);
}
__device__ __forceinline__ float bf2f(u16 h){
  unsigned u = ((unsigned)h) << 16;
  return __builtin_bit_cast(float, u);
}
__device__ __forceinline__ f32x4 mfma16(s16x8 a, s16x8 b, f32x4 c){
  return __builtin_amdgcn_mfma_f32_16x16x32_bf16(a, b, c, 0, 0, 0);
}

// ---------------- split x -> bf16 hi/lo ----------------
__global__ __launch_bounds__(256) void k_split(const float* __restrict__ x,
    u16* __restrict__ xh, u16* __restrict__ xl, int n4){
  int id = blockIdx.x*256 + threadIdx.x;
  if (id >= n4) return;
  float4 v = ((const float4*)x)[id];
  float vv[4] = {v.x, v.y, v.z, v.w};
  u16 hh[4], ll[4];
  #pragma unroll
  for (int i=0;i<4;++i){ hh[i] = f2bf(vv[i]); ll[i] = f2bf(vv[i] - bf2f(hh[i])); }
  ((ushort4*)xh)[id] = make_ushort4(hh[0],hh[1],hh[2],hh[3]);
  ((ushort4*)xl)[id] = make_ushort4(ll[0],ll[1],ll[2],ll[3]);
}

// ------------- transpose + split: in[R][C] f32 -> out[C][R] bf16 hi/lo -------------
__global__ __launch_bounds__(256) void k_tsplit(const float* __restrict__ in,
    u16* __restrict__ oh, u16* __restrict__ ol, int R, int C){
  __shared__ float tile[32][33];
  int tx = threadIdx.x & 31, ty = threadIdx.x >> 5;
  int c0 = blockIdx.x*32, r0 = blockIdx.y*32;
  #pragma unroll
  for (int rr=0; rr<4; ++rr){
    int row = ty*4 + rr;
    tile[row][tx] = in[(size_t)(r0+row)*C + (c0+tx)];
  }
  __syncthreads();
  #pragma unroll
  for (int rr=0; rr<4; ++rr){
    int row = ty*4 + rr;
    float v = tile[tx][row];
    size_t o = (size_t)(c0+row)*R + (r0+tx);
    u16 hh = f2bf(v);
    oh[o] = hh; ol[o] = f2bf(v - bf2f(hh));
  }
}

// ------------- split-bf16 GEMM: C[M][N] = A[M][K] * B[N][K]^T (3-term compensated) -------------
__global__ __launch_bounds__(256) void k_gemm(const u16* __restrict__ Ah, const u16* __restrict__ Al,
    const u16* __restrict__ Bh, const u16* __restrict__ Bl, float* __restrict__ C,
    int M, int N, int K){
  __shared__ u16 As[2][128][72];
  __shared__ u16 Bs[2][64][72];
  int t = threadIdx.x;
  int n0 = blockIdx.x*64, m0 = blockIdx.y*128;
  int w = t>>6, lane = t&63, lg = lane>>4, lr = lane&15;
  int iw = w&1, jw = w>>1;
  f32x4 acc[4][2] = {};
  for (int k0=0; k0<K; k0+=64){
    __syncthreads();
    #pragma unroll
    for (int it=0; it<4; ++it){
      int id = it*256+t; int row=id>>3, c8=id&7;
      *(uint4*)&As[0][row][c8*8] = *(const uint4*)(Ah + (size_t)(m0+row)*K + k0 + c8*8);
      *(uint4*)&As[1][row][c8*8] = *(const uint4*)(Al + (size_t)(m0+row)*K + k0 + c8*8);
    }
    #pragma unroll
    for (int it=0; it<2; ++it){
      int id = it*256+t; int row=id>>3, c8=id&7;
      *(uint4*)&Bs[0][row][c8*8] = *(const uint4*)(Bh + (size_t)(n0+row)*K + k0 + c8*8);
      *(uint4*)&Bs[1][row][c8*8] = *(const uint4*)(Bl + (size_t)(n0+row)*K + k0 + c8*8);
    }
    __syncthreads();
    #pragma unroll
    for (int ks=0; ks<2; ++ks){
      int kk = ks*32 + lg*8;
      s16x8 ah[4], al[4], bh[2], bl[2];
      #pragma unroll
      for (int m=0;m<4;++m){
        int r = iw*64 + m*16 + lr;
        ah[m] = *(const s16x8*)&As[0][r][kk];
        al[m] = *(const s16x8*)&As[1][r][kk];
      }
      #pragma unroll
      for (int nn=0;nn<2;++nn){
        int r = jw*32 + nn*16 + lr;
        bh[nn] = *(const s16x8*)&Bs[0][r][kk];
        bl[nn] = *(const s16x8*)&Bs[1][r][kk];
      }
      #pragma unroll
      for (int m=0;m<4;++m)
        #pragma unroll
        for(int nn=0;nn<2;++nn){
          acc[m][nn] = mfma16(ah[m], bh[nn], acc[m][nn]);
          acc[m][nn] = mfma16(ah[m], bl[nn], acc[m][nn]);
          acc[m][nn] = mfma16(al[m], bh[nn], acc[m][nn]);
        }
    }
  }
  #pragma unroll
  for (int m=0;m<4;++m)
    #pragma unroll
    for(int nn=0;nn<2;++nn)
      #pragma unroll
      for(int r=0;r<4;++r){
        int row = m0 + iw*64 + m*16 + lg*4 + r;
        int col = n0 + jw*32 + nn*16 + lr;
        C[(size_t)row*N + col] = acc[m][nn][r];
      }
}

// ------------- rmsnorm + rope + split/transposed layouts -------------
__device__ __forceinline__ float blocksum128(float v, float* red, int t){
  #pragma unroll
  for (int m=32; m>=1; m>>=1) v += __shfl_xor(v, m, 64);
  __syncthreads();
  if ((t&63)==0) red[t>>6] = v;
  __syncthreads();
  return red[0] + red[1];
}

__global__ __launch_bounds__(128) void k_normrope(const float* __restrict__ qkv,
   const float* __restrict__ rot, const float* __restrict__ qw, const float* __restrict__ kw,
   const float* __restrict__ vw, u16* __restrict__ Qh, u16* __restrict__ Ql,
   u16* __restrict__ Kh, u16* __restrict__ Kl, u16* __restrict__ Vt){
  __shared__ float buf[128];
  __shared__ float red[2];
  int n = blockIdx.x, t = threadIdx.x;
  const float* row = qkv + (size_t)n*1344;
  float pos = rot[(size_t)n*128 + t];
  float cs = cosf(pos), sn = sinf(pos);
  float qwt = qw[t], kwt = kw[t];
  #pragma unroll 1
  for (int h=0; h<8; ++h){
    float v = row[h*128 + t];
    float ss = blocksum128(v*v, red, t);
    float rr = rsqrtf(ss*(1.0f/128.0f) + 1.1920929e-07f);
    float qn = v*rr*qwt*0.125f;
    __syncthreads();
    buf[t] = qn;
    __syncthreads();
    float partner = (t<64) ? -buf[t+64] : buf[t-64];
    float o = qn*cs + partner*sn;
    u16 hh = f2bf(o);
    size_t oi = ((size_t)h*2048 + n)*128 + t;
    Qh[oi] = hh; Ql[oi] = f2bf(o - bf2f(hh));
  }
  {
    float v = row[1024 + t];
    float ss = blocksum128(v*v, red, t);
    float rr = rsqrtf(ss*(1.0f/128.0f) + 1.1920929e-07f);
    float kn = v*rr*kwt;
    __syncthreads();
    buf[t] = kn;
    __syncthreads();
    float partner = (t<64) ? -buf[t+64] : buf[t-64];
    float o = kn*cs + partner*sn;
    u16 hh = f2bf(o);
    size_t oi = (size_t)n*128 + t;
    Kh[oi] = hh; Kl[oi] = f2bf(o - bf2f(hh));
  }
  {
    float v0 = row[1152 + t];
    float v1 = (t<64) ? row[1280 + t] : 0.0f;
    float ss = blocksum128(v0*v0 + v1*v1, red, t);
    float rr = rsqrtf(ss*(1.0f/192.0f) + 1.1920929e-07f);
    Vt[(size_t)t*2048 + n] = f2bf(v0*rr*vw[t]);
    if (t < 64) Vt[(size_t)(128+t)*2048 + n] = f2bf(v1*rr*vw[128+t]);
  }
}

// ------------- pairwise -> attention bias v2: MFMA matvec, bias[pair][8] -------------
// gelu(exact, A&S 7.1.26 erf approx, |err|<1.5e-7) of normalized pairwise,
// then [16 pairs x 128] @ Wb[128 x 8(pad 16)] via 3-term split bf16 MFMA.
__global__ __launch_bounds__(256) void k_bias2(const float* __restrict__ pw, const float* __restrict__ rv,
  const float* __restrict__ gamma, const float* __restrict__ beta, const float* __restrict__ Wb,
  float* __restrict__ bias){
  __shared__ float As[128], Bs[128];
  int t = threadIdx.x;
  if (t < 128){
    As[t] = 11.313708498984761f * rsqrtf(fmaxf(rv[t], 1e-5f)) * (gamma[t] + 1.0f);
    Bs[t] = beta[t];
  }
  __syncthreads();
  int w = t>>6, lane = t&63, lg = lane>>4, lr = lane&15;
  // B fragments: Wb^T rows (head=lr, pad to 16), hi/lo
  s16x8 wbh[4], wbl[4];
  #pragma unroll
  for (int ks=0; ks<4; ++ks){
    s16x8 vh, vl;
    #pragma unroll
    for (int e=0; e<8; ++e){
      float v = (lr < 8) ? Wb[(ks*32 + lg*8 + e)*8 + lr] : 0.0f;
      u16 hh = f2bf(v);
      vh[e] = (short)hh;
      vl[e] = (short)f2bf(v - bf2f(hh));
    }
    wbh[ks] = vh; wbl[ks] = vl;
  }
  #pragma unroll
  for (int it=0; it<2; ++it){
    int p0 = blockIdx.x*128 + it*64 + w*16;
    const float* rowp = pw + (size_t)(p0 + lr)*128;
    f32x4 acc = {0.f,0.f,0.f,0.f};
    #pragma unroll
    for (int ks=0; ks<4; ++ks){
      int c = ks*32 + lg*8;
      float4 x0 = *(const float4*)(rowp + c);
      float4 x1 = *(const float4*)(rowp + c + 4);
      float4 a0 = *(const float4*)&As[c], a1 = *(const float4*)&As[c+4];
      float4 b0 = *(const float4*)&Bs[c], b1 = *(const float4*)&Bs[c+4];
      float xv[8] = {x0.x*a0.x+b0.x, x0.y*a0.y+b0.y, x0.z*a0.z+b0.z, x0.w*a0.w+b0.w,
                     x1.x*a1.x+b1.x, x1.y*a1.y+b1.y, x1.z*a1.z+b1.z, x1.w*a1.w+b1.w};
      s16x8 gh, gl;
      #pragma unroll
      for (int e=0; e<8; ++e){
        float v = xv[e];
        float z = v * 0.7071067811865476f;
        float s = fabsf(z);
        float tt = 1.0f / (1.0f + 0.3275911f*s);
        float poly = ((((1.061405429f*tt - 1.453152027f)*tt + 1.421413741f)*tt - 0.284496736f)*tt + 0.254829592f)*tt;
        float E = __expf(-s*s);
        float Q = 0.5f*v*poly*E;
        float ge = (v >= 0.0f) ? (v - Q) : Q;
        u16 hh = f2bf(ge);
        gh[e] = (short)hh;
        gl[e] = (short)f2bf(ge - bf2f(hh));
      }
      acc = mfma16(gh, wbh[ks], acc);
      acc = mfma16(gh, wbl[ks], acc);
      acc = mfma16(gl, wbh[ks], acc);
    }
    if (lr < 8)
      #pragma unroll
      for (int r=0; r<4; ++r)
        bias[(size_t)(p0 + lg*4 + r)*8 + lr] = acc[r];
  }
}

// ------------- fused attention v4: GQA — 4 heads/block share staged K/V -------------
__global__ __launch_bounds__(256,2) void k_attn4(const u16* __restrict__ Qh, const u16* __restrict__ Ql,
  const u16* __restrict__ Kh, const u16* __restrict__ Kl, const u16* __restrict__ Vt,
  const float* __restrict__ bias, float* __restrict__ Oacc, float* __restrict__ Sacc){
  __shared__ u16 KhS[32][136];
  __shared__ u16 KlS[32][136];
  __shared__ u16 VtS[192][40];
  __shared__ u16 PS[4][32][40];
  int t = threadIdx.x;
  int w = t>>6, lane = t&63, lg = lane>>4, lr = lane&15;
  int q0 = blockIdx.x*32;
  int h = blockIdx.y*4 + w;            // one head per wave
  int jbase = blockIdx.z*512;
  // Q fragments (hi+lo), 3-term compensated QK^T
  s16x8 qfh[2][4], qfl[2][4];
  #pragma unroll
  for (int qi=0; qi<2; ++qi){
    const u16* qb  = Qh + ((size_t)h*2048 + q0 + qi*16 + lr)*128 + lg*8;
    const u16* qb2 = Ql + ((size_t)h*2048 + q0 + qi*16 + lr)*128 + lg*8;
    #pragma unroll
    for (int ks=0; ks<4; ++ks){
      qfh[qi][ks] = *(const s16x8*)(qb  + ks*32);
      qfl[qi][ks] = *(const s16x8*)(qb2 + ks*32);
    }
  }
  // cooperative staging addresses
  int rK[2], cK[2], rV[3], cV[3];
  #pragma unroll
  for (int i=0;i<2;++i){ int id=i*256+t; rK[i]=id>>4; cK[i]=(id&15)*8; }
  #pragma unroll
  for (int i=0;i<3;++i){ int id=i*256+t; rV[i]=id>>2; cV[i]=(id&3)*8; }
  uint4 sKh[2], sKl[2], sV[3];
  auto issue = [&](int j0){
    #pragma unroll
    for (int i=0;i<2;++i){
      sKh[i] = *(const uint4*)(Kh + (size_t)(j0+rK[i])*128 + cK[i]);
      sKl[i] = *(const uint4*)(Kl + (size_t)(j0+rK[i])*128 + cK[i]);
    }
    #pragma unroll
    for (int i=0;i<3;++i)
      sV[i] = *(const uint4*)(Vt + (size_t)rV[i]*2048 + j0 + cV[i]);
  };
  issue(jbase);
  f32x4 accO[2][12] = {};
  float psum[2][4] = {};
  int bRow = (q0>>2) + lg;             // + qi*4 ; constant over r
  for (int jt=0; jt<16; ++jt){
    int j0 = jbase + jt*32;
    __syncthreads();                   // all waves done reading prev K/V
    #pragma unroll
    for (int i=0;i<2;++i){
      *(uint4*)&KhS[rK[i]][cK[i]] = sKh[i];
      *(uint4*)&KlS[rK[i]][cK[i]] = sKl[i];
    }
    #pragma unroll
    for (int i=0;i<3;++i) *(uint4*)&VtS[rV[i]][cV[i]] = sV[i];
    __syncthreads();                   // staged tile visible
    if (jt < 15) issue(j0 + 32);       // prefetch next tile into regs
    // QK^T : A=Q rows, B=K rows
    f32x4 accS[2][2] = {};
    #pragma unroll
    for (int ks=0; ks<4; ++ks){
      int kk = ks*32 + lg*8;
      s16x8 kbh[2], kbl[2];
      #pragma unroll
      for (int kj=0; kj<2; ++kj){
        kbh[kj] = *(const s16x8*)&KhS[kj*16+lr][kk];
        kbl[kj] = *(const s16x8*)&KlS[kj*16+lr][kk];
      }
      #pragma unroll
      for (int qi=0; qi<2; ++qi)
        #pragma unroll
        for (int kj=0; kj<2; ++kj){
          accS[qi][kj] = mfma16(qfh[qi][ks], kbh[kj], accS[qi][kj]);
          accS[qi][kj] = mfma16(qfh[qi][ks], kbl[kj], accS[qi][kj]);
          accS[qi][kj] = mfma16(qfl[qi][ks], kbh[kj], accS[qi][kj]);
        }
    }
    // bias + softcap exp + P write (per-wave buffer, no barrier)
    #pragma unroll
    for (int qi=0; qi<2; ++qi)
      #pragma unroll
      for (int kj=0; kj<2; ++kj){
        float bv = bias[((size_t)(bRow + qi*4)*512 + ((j0 + kj*16)>>2) + (lr>>2))*8 + h];
        #pragma unroll
        for (int r=0; r<4; ++r){
          float s = accS[qi][kj][r] + bv;
          // p = exp(5*tanh(s/5)) = e^5 * exp(-10/(e^{0.4 s}+1))
          float te = __expf(0.4f*s);
          float ri; asm("v_rcp_f32 %0, %1" : "=v"(ri) : "v"(te + 1.0f));
          float p = 148.4131591f * __expf(-10.0f*ri);
          psum[qi][r] += p;
          PS[w][qi*16+lg*4+r][kj*16+lr] = f2bf(p);
        }
      }
    // PV : A=P (K=32 keys), B=V^T tile
    #pragma unroll
    for (int qi=0; qi<2; ++qi){
      s16x8 pa = *(const s16x8*)&PS[w][qi*16+lr][lg*8];
      #pragma unroll
      for (int df=0; df<12; ++df){
        s16x8 vb = *(const s16x8*)&VtS[df*16+lr][lg*8];
        accO[qi][df] = mfma16(pa, vb, accO[qi][df]);
      }
    }
  }
  // row-sum partials
  #pragma unroll
  for (int qi=0; qi<2; ++qi){
    #pragma unroll
    for (int m=1; m<16; m<<=1)
      #pragma unroll
      for (int r=0; r<4; ++r) psum[qi][r] += __shfl_xor(psum[qi][r], m, 64);
    if (lr == 0)
      #pragma unroll
      for (int r=0; r<4; ++r)
        atomicAdd(&Sacc[h*2048 + q0 + qi*16 + lg*4 + r], psum[qi][r]);
  }
  // output partials
  #pragma unroll
  for (int qi=0; qi<2; ++qi)
    #pragma unroll
    for (int df=0; df<12; ++df)
      #pragma unroll
      for (int r=0; r<4; ++r)
        atomicAdd(&Oacc[((size_t)h*2048 + q0 + qi*16 + lg*4 + r)*192 + df*16 + lr], accO[qi][df][r]);
}

// ------------- normalize partials, relayout to [q][h*192+d], bf16 hi/lo split -------------
__global__ __launch_bounds__(256) void k_attnred(const float* __restrict__ Oacc,
    const float* __restrict__ Sacc, u16* __restrict__ Oh, u16* __restrict__ Ol){
  int id = blockIdx.x*256 + threadIdx.x;   // 8*2048*48 threads, 4 d each
  float4 a = ((const float4*)Oacc)[id];
  int hq = id / 48;
  int d4 = id - hq*48;
  float inv = 1.0f / Sacc[hq];
  int hh = hq >> 11, q = hq & 2047;
  size_t o = (size_t)q*1536 + hh*192 + d4*4;
  float vv[4] = {a.x, a.y, a.z, a.w};
  u16 rh[4], rl[4];
  #pragma unroll
  for (int j=0; j<4; ++j){
    float v = vv[j]*inv;
    rh[j] = f2bf(v);
    rl[j] = f2bf(v - bf2f(rh[j]));
  }
  *(ushort4*)(Oh+o) = make_ushort4(rh[0],rh[1],rh[2],rh[3]);
  *(ushort4*)(Ol+o) = make_ushort4(rl[0],rl[1],rl[2],rl[3]);
}

extern "C" void kernel_launch(void* const* d_in, const int* in_sizes, int n_in,
                              void* d_out, int out_size, void* d_ws, size_t ws_size,
                              hipStream_t stream){
  (void)in_sizes; (void)n_in; (void)out_size; (void)ws_size;
  const float* x   = (const float*)d_in[0];
  const float* pwi = (const float*)d_in[1];
  const float* rot = (const float*)d_in[2];
  const float* Wq  = (const float*)d_in[3];
  const float* qw  = (const float*)d_in[4];
  const float* kw  = (const float*)d_in[5];
  const float* vw  = (const float*)d_in[6];
  const float* gm  = (const float*)d_in[7];
  const float* bt  = (const float*)d_in[8];
  const float* rvv = (const float*)d_in[9];
  const float* Wb  = (const float*)d_in[10];
  const float* Wo  = (const float*)d_in[11];
  float* out = (float*)d_out;
  char* ws = (char*)d_ws;
  size_t off = 0;
  auto alloc = [&](size_t bytes)->char*{
    char* p = ws + off; off = (off + bytes + 255) & ~(size_t)255; return p;
  };
  u16* xh  = (u16*)alloc(2048ull*1024*2);
  u16* xl  = (u16*)alloc(2048ull*1024*2);
  u16* Wqh = (u16*)alloc(1344ull*1024*2);
  u16* Wql = (u16*)alloc(1344ull*1024*2);
  u16* Woh = (u16*)alloc(1024ull*1536*2);
  u16* Wol = (u16*)alloc(1024ull*1536*2);
  float* qkv = (float*)alloc(2048ull*1344*4);
  u16* Qhb = (u16*)alloc(8ull*2048*128*2);
  u16* Qlb = (u16*)alloc(8ull*2048*128*2);
  u16* Khb = (u16*)alloc(2048ull*128*2);
  u16* Klb = (u16*)alloc(2048ull*128*2);
  u16* Vtb = (u16*)alloc(192ull*2048*2);
  float* bias = (float*)alloc(8ull*512*512*4);   // layout [pair][8]
  u16* Ohb = (u16*)alloc(2048ull*1536*2);
  u16* Olb = (u16*)alloc(2048ull*1536*2);
  // Oacc/Sacc alias the [xh, xl, Wqh, Wql] region (13.9 MB), dead after gemm1.
  float* Oacc = (float*)ws;                               // [8][2048][192] f32
  float* Sacc = (float*)(ws + 8ull*2048*192*4);           // [8][2048] f32

  k_split<<<2048, 256, 0, stream>>>(x, xh, xl, 524288);
  k_tsplit<<<dim3(1344/32, 1024/32), 256, 0, stream>>>(Wq, Wqh, Wql, 1024, 1344);
  k_tsplit<<<dim3(1024/32, 1536/32), 256, 0, stream>>>(Wo, Woh, Wol, 1536, 1024);
  k_gemm<<<dim3(1344/64, 2048/128), 256, 0, stream>>>(xh, xl, Wqh, Wql, qkv, 2048, 1344, 1024);
  hipMemsetAsync(Oacc, 0, (8ull*2048*192 + 8ull*2048)*4, stream);
  k_normrope<<<2048, 128, 0, stream>>>(qkv, rot, qw, kw, vw, Qhb, Qlb, Khb, Klb, Vtb);
  k_bias2<<<2048, 256, 0, stream>>>(pwi, rvv, gm, bt, Wb, bias);
  k_attn4<<<dim3(64, 2, 4), 256, 0, stream>>>(Qhb, Qlb, Khb, Klb, Vtb, bias, Oacc, Sacc);
  k_attnred<<<3072, 256, 0, stream>>>(Oacc, Sacc, Ohb, Olb);
  k_gemm<<<dim3(1024/64, 2048/128), 256, 0, stream>>>(Ohb, Olb, Woh, Wol, out, 2048, 1024, 1536);
}

// Round 6
// 254.367 us; speedup vs baseline: 1.7932x; 1.0726x over previous
//
#include <hip/hip_runtime.h>
#include <math.h>

typedef unsigned short u16;
typedef __attribute__((ext_vector_type(4))) float f32x4;
typedef __attribute__((ext_vector_type(8))) short s16x8;
typedef __attribute__((ext_vector_type(8))) _Float16 f16x8;

__device__ __forceinline__ u16 f2bf(float f){
  unsigned u = __builtin_bit_cast(unsigned, f);
  u += 0x7fffu + ((u >> 16) & 1u);
  return (u16)(u >> 16);
}
__device__ __forceinline__ float bf2f(u16 h){
  unsigned u = ((unsigned)h) << 16;
  return __builtin_bit_cast(float, u);
}
__device__ __forceinline__ u16 f2h(float f){
  return __builtin_bit_cast(u16, (_Float16)f);
}
__device__ __forceinline__ f32x4 mfma16(s16x8 a, s16x8 b, f32x4 c){
  return __builtin_amdgcn_mfma_f32_16x16x32_bf16(a, b, c, 0, 0, 0);
}
__device__ __forceinline__ f32x4 mfma16h(f16x8 a, f16x8 b, f32x4 c){
  return __builtin_amdgcn_mfma_f32_16x16x32_f16(a, b, c, 0, 0, 0);
}

// ---------------- split x -> bf16 hi/lo ----------------
__global__ __launch_bounds__(256) void k_split(const float* __restrict__ x,
    u16* __restrict__ xh, u16* __restrict__ xl, int n4){
  int id = blockIdx.x*256 + threadIdx.x;
  if (id >= n4) return;
  float4 v = ((const float4*)x)[id];
  float vv[4] = {v.x, v.y, v.z, v.w};
  u16 hh[4], ll[4];
  #pragma unroll
  for (int i=0;i<4;++i){ hh[i] = f2bf(vv[i]); ll[i] = f2bf(vv[i] - bf2f(hh[i])); }
  ((ushort4*)xh)[id] = make_ushort4(hh[0],hh[1],hh[2],hh[3]);
  ((ushort4*)xl)[id] = make_ushort4(ll[0],ll[1],ll[2],ll[3]);
}

// ------------- transpose + split: in[R][C] f32 -> out[C][R] bf16 hi/lo -------------
__global__ __launch_bounds__(256) void k_tsplit(const float* __restrict__ in,
    u16* __restrict__ oh, u16* __restrict__ ol, int R, int C){
  __shared__ float tile[32][33];
  int tx = threadIdx.x & 31, ty = threadIdx.x >> 5;
  int c0 = blockIdx.x*32, r0 = blockIdx.y*32;
  #pragma unroll
  for (int rr=0; rr<4; ++rr){
    int row = ty*4 + rr;
    tile[row][tx] = in[(size_t)(r0+row)*C + (c0+tx)];
  }
  __syncthreads();
  #pragma unroll
  for (int rr=0; rr<4; ++rr){
    int row = ty*4 + rr;
    float v = tile[tx][row];
    size_t o = (size_t)(c0+row)*R + (r0+tx);
    u16 hh = f2bf(v);
    oh[o] = hh; ol[o] = f2bf(v - bf2f(hh));
  }
}

// ------------- split-bf16 GEMM: C[M][N] = A[M][K] * B[N][K]^T (3-term compensated) -------------
__global__ __launch_bounds__(256) void k_gemm(const u16* __restrict__ Ah, const u16* __restrict__ Al,
    const u16* __restrict__ Bh, const u16* __restrict__ Bl, float* __restrict__ C,
    int M, int N, int K){
  __shared__ u16 As[2][128][72];
  __shared__ u16 Bs[2][64][72];
  int t = threadIdx.x;
  int n0 = blockIdx.x*64, m0 = blockIdx.y*128;
  int w = t>>6, lane = t&63, lg = lane>>4, lr = lane&15;
  int iw = w&1, jw = w>>1;
  f32x4 acc[4][2] = {};
  for (int k0=0; k0<K; k0+=64){
    __syncthreads();
    #pragma unroll
    for (int it=0; it<4; ++it){
      int id = it*256+t; int row=id>>3, c8=id&7;
      *(uint4*)&As[0][row][c8*8] = *(const uint4*)(Ah + (size_t)(m0+row)*K + k0 + c8*8);
      *(uint4*)&As[1][row][c8*8] = *(const uint4*)(Al + (size_t)(m0+row)*K + k0 + c8*8);
    }
    #pragma unroll
    for (int it=0; it<2; ++it){
      int id = it*256+t; int row=id>>3, c8=id&7;
      *(uint4*)&Bs[0][row][c8*8] = *(const uint4*)(Bh + (size_t)(n0+row)*K + k0 + c8*8);
      *(uint4*)&Bs[1][row][c8*8] = *(const uint4*)(Bl + (size_t)(n0+row)*K + k0 + c8*8);
    }
    __syncthreads();
    #pragma unroll
    for (int ks=0; ks<2; ++ks){
      int kk = ks*32 + lg*8;
      s16x8 ah[4], al[4], bh[2], bl[2];
      #pragma unroll
      for (int m=0;m<4;++m){
        int r = iw*64 + m*16 + lr;
        ah[m] = *(const s16x8*)&As[0][r][kk];
        al[m] = *(const s16x8*)&As[1][r][kk];
      }
      #pragma unroll
      for (int nn=0;nn<2;++nn){
        int r = jw*32 + nn*16 + lr;
        bh[nn] = *(const s16x8*)&Bs[0][r][kk];
        bl[nn] = *(const s16x8*)&Bs[1][r][kk];
      }
      #pragma unroll
      for (int m=0;m<4;++m)
        #pragma unroll
        for(int nn=0;nn<2;++nn){
          acc[m][nn] = mfma16(ah[m], bh[nn], acc[m][nn]);
          acc[m][nn] = mfma16(ah[m], bl[nn], acc[m][nn]);
          acc[m][nn] = mfma16(al[m], bh[nn], acc[m][nn]);
        }
    }
  }
  #pragma unroll
  for (int m=0;m<4;++m)
    #pragma unroll
    for(int nn=0;nn<2;++nn)
      #pragma unroll
      for(int r=0;r<4;++r){
        int row = m0 + iw*64 + m*16 + lg*4 + r;
        int col = n0 + jw*32 + nn*16 + lr;
        C[(size_t)row*N + col] = acc[m][nn][r];
      }
}

// ------------- rmsnorm + rope -> fp16 Q/K and fp16 V^T -------------
__device__ __forceinline__ float blocksum128(float v, float* red, int t){
  #pragma unroll
  for (int m=32; m>=1; m>>=1) v += __shfl_xor(v, m, 64);
  __syncthreads();
  if ((t&63)==0) red[t>>6] = v;
  __syncthreads();
  return red[0] + red[1];
}

__global__ __launch_bounds__(128) void k_normrope(const float* __restrict__ qkv,
   const float* __restrict__ rot, const float* __restrict__ qw, const float* __restrict__ kw,
   const float* __restrict__ vw, u16* __restrict__ Qf,
   u16* __restrict__ Kf, u16* __restrict__ Vtf){
  __shared__ float buf[128];
  __shared__ float red[2];
  int n = blockIdx.x, t = threadIdx.x;
  const float* row = qkv + (size_t)n*1344;
  float pos = rot[(size_t)n*128 + t];
  float cs = cosf(pos), sn = sinf(pos);
  float qwt = qw[t], kwt = kw[t];
  #pragma unroll 1
  for (int h=0; h<8; ++h){
    float v = row[h*128 + t];
    float ss = blocksum128(v*v, red, t);
    float rr = rsqrtf(ss*(1.0f/128.0f) + 1.1920929e-07f);
    float qn = v*rr*qwt*0.125f;
    __syncthreads();
    buf[t] = qn;
    __syncthreads();
    float partner = (t<64) ? -buf[t+64] : buf[t-64];
    float o = qn*cs + partner*sn;
    Qf[((size_t)h*2048 + n)*128 + t] = f2h(o);
  }
  {
    float v = row[1024 + t];
    float ss = blocksum128(v*v, red, t);
    float rr = rsqrtf(ss*(1.0f/128.0f) + 1.1920929e-07f);
    float kn = v*rr*kwt;
    __syncthreads();
    buf[t] = kn;
    __syncthreads();
    float partner = (t<64) ? -buf[t+64] : buf[t-64];
    float o = kn*cs + partner*sn;
    Kf[(size_t)n*128 + t] = f2h(o);
  }
  {
    float v0 = row[1152 + t];
    float v1 = (t<64) ? row[1280 + t] : 0.0f;
    float ss = blocksum128(v0*v0 + v1*v1, red, t);
    float rr = rsqrtf(ss*(1.0f/192.0f) + 1.1920929e-07f);
    Vtf[(size_t)t*2048 + n] = f2h(v0*rr*vw[t]);
    if (t < 64) Vtf[(size_t)(128+t)*2048 + n] = f2h(v1*rr*vw[128+t]);
  }
}

// ------------- pairwise -> attention bias v2: MFMA matvec, bias[pair][8] -------------
__global__ __launch_bounds__(256) void k_bias2(const float* __restrict__ pw, const float* __restrict__ rv,
  const float* __restrict__ gamma, const float* __restrict__ beta, const float* __restrict__ Wb,
  float* __restrict__ bias){
  __shared__ float As[128], Bs[128];
  int t = threadIdx.x;
  if (t < 128){
    As[t] = 11.313708498984761f * rsqrtf(fmaxf(rv[t], 1e-5f)) * (gamma[t] + 1.0f);
    Bs[t] = beta[t];
  }
  __syncthreads();
  int w = t>>6, lane = t&63, lg = lane>>4, lr = lane&15;
  s16x8 wbh[4], wbl[4];
  #pragma unroll
  for (int ks=0; ks<4; ++ks){
    s16x8 vh, vl;
    #pragma unroll
    for (int e=0; e<8; ++e){
      float v = (lr < 8) ? Wb[(ks*32 + lg*8 + e)*8 + lr] : 0.0f;
      u16 hh = f2bf(v);
      vh[e] = (short)hh;
      vl[e] = (short)f2bf(v - bf2f(hh));
    }
    wbh[ks] = vh; wbl[ks] = vl;
  }
  #pragma unroll
  for (int it=0; it<2; ++it){
    int p0 = blockIdx.x*128 + it*64 + w*16;
    const float* rowp = pw + (size_t)(p0 + lr)*128;
    f32x4 acc = {0.f,0.f,0.f,0.f};
    #pragma unroll
    for (int ks=0; ks<4; ++ks){
      int c = ks*32 + lg*8;
      float4 x0 = *(const float4*)(rowp + c);
      float4 x1 = *(const float4*)(rowp + c + 4);
      float4 a0 = *(const float4*)&As[c], a1 = *(const float4*)&As[c+4];
      float4 b0 = *(const float4*)&Bs[c], b1 = *(const float4*)&Bs[c+4];
      float xv[8] = {x0.x*a0.x+b0.x, x0.y*a0.y+b0.y, x0.z*a0.z+b0.z, x0.w*a0.w+b0.w,
                     x1.x*a1.x+b1.x, x1.y*a1.y+b1.y, x1.z*a1.z+b1.z, x1.w*a1.w+b1.w};
      s16x8 gh, gl;
      #pragma unroll
      for (int e=0; e<8; ++e){
        float v = xv[e];
        float z = v * 0.7071067811865476f;
        float s = fabsf(z);
        float tt = 1.0f / (1.0f + 0.3275911f*s);
        float poly = ((((1.061405429f*tt - 1.453152027f)*tt + 1.421413741f)*tt - 0.284496736f)*tt + 0.254829592f)*tt;
        float E = __expf(-s*s);
        float Q = 0.5f*v*poly*E;
        float ge = (v >= 0.0f) ? (v - Q) : Q;
        u16 hh = f2bf(ge);
        gh[e] = (short)hh;
        gl[e] = (short)f2bf(ge - bf2f(hh));
      }
      acc = mfma16(gh, wbh[ks], acc);
      acc = mfma16(gh, wbl[ks], acc);
      acc = mfma16(gl, wbh[ks], acc);
    }
    if (lr < 8)
      #pragma unroll
      for (int r=0; r<4; ++r)
        bias[(size_t)(p0 + lg*4 + r)*8 + lr] = acc[r];
  }
}

// ------------- fused attention v5: fp16, 8 waves = 4 heads x 2 key-halves, -------------
// ------------- in-block combine, direct bf16 hi/lo output, ZERO atomics    -------------
// LDS (u16 units): KS [2][32][136] @0 (8704); VtS [2][192][40] @8704 (15360);
//                  PS [8][16][40] @24064 (5120). Total 29184 u16 = 58368 B.
// Combine phase aliases OS(float[4][16][200]) + SS(float[64]) over KS/VtS (dead).
__global__ __launch_bounds__(512,2) void k_attn5(const u16* __restrict__ Qf,
  const u16* __restrict__ Kf, const u16* __restrict__ Vtf,
  const float* __restrict__ bias, u16* __restrict__ Oh, u16* __restrict__ Ol){
  __shared__ u16 lds[29184];
  int t = threadIdx.x;
  int w = t>>6, lane = t&63, lg = lane>>4, lr = lane&15;
  int hb = w&3, hf = w>>2;
  int h = blockIdx.y*4 + hb;
  int q0 = blockIdx.x*16;
  // Q fragments (fp16)
  f16x8 qf[4];
  {
    const u16* qb = Qf + ((size_t)h*2048 + q0 + lr)*128 + lg*8;
    #pragma unroll
    for (int ks=0; ks<4; ++ks) qf[ks] = *(const f16x8*)(qb + ks*32);
  }
  // staging decomposition (512 threads): K = 1024 chunks, V = 1536 chunks
  int rK[2], cK[2], hK[2], rV[3], cV[3], hV[3];
  #pragma unroll
  for (int i=0;i<2;++i){
    int id = i*512 + t; hK[i] = id>>9; int rid = id&511;
    rK[i] = rid>>4; cK[i] = (rid&15)*8;
  }
  #pragma unroll
  for (int i=0;i<3;++i){
    int id = i*512 + t; hV[i] = (id >= 768) ? 1 : 0; int rid = id - hV[i]*768;
    rV[i] = rid>>2; cV[i] = (rid&3)*8;
  }
  uint4 sK[2], sV[3];
  auto issue = [&](int j0){
    #pragma unroll
    for (int i=0;i<2;++i)
      sK[i] = *(const uint4*)(Kf + ((size_t)(hK[i]*1024 + j0 + rK[i]))*128 + cK[i]);
    #pragma unroll
    for (int i=0;i<3;++i)
      sV[i] = *(const uint4*)(Vtf + (size_t)rV[i]*2048 + hV[i]*1024 + j0 + cV[i]);
  };
  float bCur[2], bNxt[2];
  int bRow = (q0>>2) + lg;
  auto loadBias = [&](int j0, float* bb){
    #pragma unroll
    for (int kj=0; kj<2; ++kj)
      bb[kj] = bias[((size_t)bRow*512 + ((hf*1024 + j0 + kj*16)>>2) + (lr>>2))*8 + h];
  };
  issue(0); loadBias(0, bCur);
  f32x4 accO[12] = {};
  float psum[4] = {0.f,0.f,0.f,0.f};
  for (int jt=0; jt<32; ++jt){
    int j0 = jt*32;
    __syncthreads();                    // all waves done reading prev tile
    #pragma unroll
    for (int i=0;i<2;++i)
      *(uint4*)&lds[hK[i]*4352 + rK[i]*136 + cK[i]] = sK[i];
    #pragma unroll
    for (int i=0;i<3;++i)
      *(uint4*)&lds[8704 + hV[i]*7680 + rV[i]*40 + cV[i]] = sV[i];
    __syncthreads();                    // staged tile visible
    if (jt < 31){ issue(j0 + 32); loadBias(j0 + 32, bNxt); }
    // QK^T: A = Q rows (m=lr), B = K rows (n=lr)
    f32x4 accS[2] = {};
    #pragma unroll
    for (int ks=0; ks<4; ++ks){
      int kk = ks*32 + lg*8;
      f16x8 kb0 = *(const f16x8*)&lds[hf*4352 + lr*136 + kk];
      f16x8 kb1 = *(const f16x8*)&lds[hf*4352 + (16+lr)*136 + kk];
      accS[0] = mfma16h(qf[ks], kb0, accS[0]);
      accS[1] = mfma16h(qf[ks], kb1, accS[1]);
    }
    // bias + softcap exp + P write (per-wave buffer)
    #pragma unroll
    for (int kj=0; kj<2; ++kj){
      float bv = bCur[kj];
      #pragma unroll
      for (int r=0; r<4; ++r){
        float s = accS[kj][r] + bv;
        // p = exp(5*tanh(s/5)) = e^5 * exp(-10/(e^{0.4 s}+1))
        float te = __expf(0.4f*s);
        float ri; asm("v_rcp_f32 %0, %1" : "=v"(ri) : "v"(te + 1.0f));
        float p = 148.4131591f * __expf(-10.0f*ri);
        psum[r] += p;
        lds[24064 + w*640 + (lg*4+r)*40 + kj*16+lr] = f2h(p);
      }
    }
    // PV: A = P (m=q-row, k=32 keys), B = V^T tile (n=d)
    f16x8 pa = *(const f16x8*)&lds[24064 + w*640 + lr*40 + lg*8];
    #pragma unroll
    for (int df=0; df<12; ++df){
      f16x8 vb = *(const f16x8*)&lds[8704 + hf*7680 + (df*16+lr)*40 + lg*8];
      accO[df] = mfma16h(pa, vb, accO[df]);
    }
    bCur[0] = bNxt[0]; bCur[1] = bNxt[1];
  }
  // reduce psum across lr (rows are lg*4+r)
  #pragma unroll
  for (int m=1; m<16; m<<=1)
    #pragma unroll
    for (int r=0; r<4; ++r) psum[r] += __shfl_xor(psum[r], m, 64);
  __syncthreads();                      // staging LDS now dead; alias as OS/SS
  float* OS = (float*)lds;              // [4][16][200]
  float* SS = OS + 12800;               // [64]
  if (hf){
    #pragma unroll
    for (int df=0; df<12; ++df)
      #pragma unroll
      for (int r=0; r<4; ++r)
        OS[(hb*16 + lg*4 + r)*200 + df*16 + lr] = accO[df][r];
    if (lr == 0)
      #pragma unroll
      for (int r=0; r<4; ++r) SS[hb*16 + lg*4 + r] = psum[r];
  }
  __syncthreads();
  if (!hf){
    float inv[4];
    #pragma unroll
    for (int r=0; r<4; ++r)
      inv[r] = 1.0f / (psum[r] + SS[hb*16 + lg*4 + r]);
    #pragma unroll
    for (int df=0; df<12; ++df)
      #pragma unroll
      for (int r=0; r<4; ++r){
        float o = (accO[df][r] + OS[(hb*16 + lg*4 + r)*200 + df*16 + lr]) * inv[r];
        int row = q0 + lg*4 + r;
        int col = h*192 + df*16 + lr;
        u16 hh2 = f2bf(o);
        size_t oi = (size_t)row*1536 + col;
        Oh[oi] = hh2; Ol[oi] = f2bf(o - bf2f(hh2));
      }
  }
}

extern "C" void kernel_launch(void* const* d_in, const int* in_sizes, int n_in,
                              void* d_out, int out_size, void* d_ws, size_t ws_size,
                              hipStream_t stream){
  (void)in_sizes; (void)n_in; (void)out_size; (void)ws_size;
  const float* x   = (const float*)d_in[0];
  const float* pwi = (const float*)d_in[1];
  const float* rot = (const float*)d_in[2];
  const float* Wq  = (const float*)d_in[3];
  const float* qw  = (const float*)d_in[4];
  const float* kw  = (const float*)d_in[5];
  const float* vw  = (const float*)d_in[6];
  const float* gm  = (const float*)d_in[7];
  const float* bt  = (const float*)d_in[8];
  const float* rvv = (const float*)d_in[9];
  const float* Wb  = (const float*)d_in[10];
  const float* Wo  = (const float*)d_in[11];
  float* out = (float*)d_out;
  char* ws = (char*)d_ws;
  size_t off = 0;
  auto alloc = [&](size_t bytes)->char*{
    char* p = ws + off; off = (off + bytes + 255) & ~(size_t)255; return p;
  };
  u16* xh  = (u16*)alloc(2048ull*1024*2);
  u16* xl  = (u16*)alloc(2048ull*1024*2);
  u16* Wqh = (u16*)alloc(1344ull*1024*2);
  u16* Wql = (u16*)alloc(1344ull*1024*2);
  u16* Woh = (u16*)alloc(1024ull*1536*2);
  u16* Wol = (u16*)alloc(1024ull*1536*2);
  float* qkv = (float*)alloc(2048ull*1344*4);
  u16* Qfb = (u16*)alloc(8ull*2048*128*2);
  u16* Kfb = (u16*)alloc(2048ull*128*2);
  u16* Vtb = (u16*)alloc(192ull*2048*2);
  float* bias = (float*)alloc(8ull*512*512*4);   // layout [pair][8]
  u16* Ohb = (u16*)alloc(2048ull*1536*2);
  u16* Olb = (u16*)alloc(2048ull*1536*2);

  k_split<<<2048, 256, 0, stream>>>(x, xh, xl, 524288);
  k_tsplit<<<dim3(1344/32, 1024/32), 256, 0, stream>>>(Wq, Wqh, Wql, 1024, 1344);
  k_tsplit<<<dim3(1024/32, 1536/32), 256, 0, stream>>>(Wo, Woh, Wol, 1536, 1024);
  k_gemm<<<dim3(1344/64, 2048/128), 256, 0, stream>>>(xh, xl, Wqh, Wql, qkv, 2048, 1344, 1024);
  k_normrope<<<2048, 128, 0, stream>>>(qkv, rot, qw, kw, vw, Qfb, Kfb, Vtb);
  k_bias2<<<2048, 256, 0, stream>>>(pwi, rvv, gm, bt, Wb, bias);
  k_attn5<<<dim3(128, 2), 512, 0, stream>>>(Qfb, Kfb, Vtb, bias, Ohb, Olb);
  k_gemm<<<dim3(1024/64, 2048/128), 256, 0, stream>>>(Ohb, Olb, Woh, Wol, out, 2048, 1024, 1536);
}

// Round 7
// 178.593 us; speedup vs baseline: 2.5540x; 1.4243x over previous
//
#include <hip/hip_runtime.h>
#include <math.h>

typedef unsigned short u16;
typedef __attribute__((ext_vector_type(4))) float f32x4;
typedef __attribute__((ext_vector_type(8))) short s16x8;
typedef __attribute__((ext_vector_type(8))) _Float16 f16x8;

__device__ __forceinline__ u16 f2bf(float f){
  unsigned u = __builtin_bit_cast(unsigned, f);
  u += 0x7fffu + ((u >> 16) & 1u);
  return (u16)(u >> 16);
}
__device__ __forceinline__ float bf2f(u16 h){
  unsigned u = ((unsigned)h) << 16;
  return __builtin_bit_cast(float, u);
}
__device__ __forceinline__ u16 f2h(float f){
  return __builtin_bit_cast(u16, (_Float16)f);
}
__device__ __forceinline__ float h2f(u16 h){
  return (float)__builtin_bit_cast(_Float16, h);
}
__device__ __forceinline__ f32x4 mfma16(s16x8 a, s16x8 b, f32x4 c){
  return __builtin_amdgcn_mfma_f32_16x16x32_bf16(a, b, c, 0, 0, 0);
}
__device__ __forceinline__ f32x4 mfma16h(f16x8 a, f16x8 b, f32x4 c){
  return __builtin_amdgcn_mfma_f32_16x16x32_f16(a, b, c, 0, 0, 0);
}
__device__ __forceinline__ void gload16(const void* src, const u16* ldsbase){
  __builtin_amdgcn_global_load_lds(
      (const __attribute__((address_space(1))) void*)src,
      (__attribute__((address_space(3))) void*)ldsbase, 16, 0, 0);
}

// ---------------- split x -> bf16 hi/lo ----------------
__global__ __launch_bounds__(256) void k_split(const float* __restrict__ x,
    u16* __restrict__ xh, u16* __restrict__ xl, int n4){
  int id = blockIdx.x*256 + threadIdx.x;
  if (id >= n4) return;
  float4 v = ((const float4*)x)[id];
  float vv[4] = {v.x, v.y, v.z, v.w};
  u16 hh[4], ll[4];
  #pragma unroll
  for (int i=0;i<4;++i){ hh[i] = f2bf(vv[i]); ll[i] = f2bf(vv[i] - bf2f(hh[i])); }
  ((ushort4*)xh)[id] = make_ushort4(hh[0],hh[1],hh[2],hh[3]);
  ((ushort4*)xl)[id] = make_ushort4(ll[0],ll[1],ll[2],ll[3]);
}

// ------------- transpose + split: in[R][C] f32 -> out[C][R] bf16 hi/lo -------------
__global__ __launch_bounds__(256) void k_tsplit(const float* __restrict__ in,
    u16* __restrict__ oh, u16* __restrict__ ol, int R, int C){
  __shared__ float tile[32][33];
  int tx = threadIdx.x & 31, ty = threadIdx.x >> 5;
  int c0 = blockIdx.x*32, r0 = blockIdx.y*32;
  #pragma unroll
  for (int rr=0; rr<4; ++rr){
    int row = ty*4 + rr;
    tile[row][tx] = in[(size_t)(r0+row)*C + (c0+tx)];
  }
  __syncthreads();
  #pragma unroll
  for (int rr=0; rr<4; ++rr){
    int row = ty*4 + rr;
    float v = tile[tx][row];
    size_t o = (size_t)(c0+row)*R + (r0+tx);
    u16 hh = f2bf(v);
    oh[o] = hh; ol[o] = f2bf(v - bf2f(hh));
  }
}

// ------------- split-bf16 GEMM: C[M][N] = A[M][K] * B[N][K]^T (3-term compensated) -------------
__global__ __launch_bounds__(256) void k_gemm(const u16* __restrict__ Ah, const u16* __restrict__ Al,
    const u16* __restrict__ Bh, const u16* __restrict__ Bl, float* __restrict__ C,
    int M, int N, int K){
  __shared__ u16 As[2][128][72];
  __shared__ u16 Bs[2][64][72];
  int t = threadIdx.x;
  int n0 = blockIdx.x*64, m0 = blockIdx.y*128;
  int w = t>>6, lane = t&63, lg = lane>>4, lr = lane&15;
  int iw = w&1, jw = w>>1;
  f32x4 acc[4][2] = {};
  for (int k0=0; k0<K; k0+=64){
    __syncthreads();
    #pragma unroll
    for (int it=0; it<4; ++it){
      int id = it*256+t; int row=id>>3, c8=id&7;
      *(uint4*)&As[0][row][c8*8] = *(const uint4*)(Ah + (size_t)(m0+row)*K + k0 + c8*8);
      *(uint4*)&As[1][row][c8*8] = *(const uint4*)(Al + (size_t)(m0+row)*K + k0 + c8*8);
    }
    #pragma unroll
    for (int it=0; it<2; ++it){
      int id = it*256+t; int row=id>>3, c8=id&7;
      *(uint4*)&Bs[0][row][c8*8] = *(const uint4*)(Bh + (size_t)(n0+row)*K + k0 + c8*8);
      *(uint4*)&Bs[1][row][c8*8] = *(const uint4*)(Bl + (size_t)(n0+row)*K + k0 + c8*8);
    }
    __syncthreads();
    #pragma unroll
    for (int ks=0; ks<2; ++ks){
      int kk = ks*32 + lg*8;
      s16x8 ah[4], al[4], bh[2], bl[2];
      #pragma unroll
      for (int m=0;m<4;++m){
        int r = iw*64 + m*16 + lr;
        ah[m] = *(const s16x8*)&As[0][r][kk];
        al[m] = *(const s16x8*)&As[1][r][kk];
      }
      #pragma unroll
      for (int nn=0;nn<2;++nn){
        int r = jw*32 + nn*16 + lr;
        bh[nn] = *(const s16x8*)&Bs[0][r][kk];
        bl[nn] = *(const s16x8*)&Bs[1][r][kk];
      }
      #pragma unroll
      for (int m=0;m<4;++m)
        #pragma unroll
        for(int nn=0;nn<2;++nn){
          acc[m][nn] = mfma16(ah[m], bh[nn], acc[m][nn]);
          acc[m][nn] = mfma16(ah[m], bl[nn], acc[m][nn]);
          acc[m][nn] = mfma16(al[m], bh[nn], acc[m][nn]);
        }
    }
  }
  #pragma unroll
  for (int m=0;m<4;++m)
    #pragma unroll
    for(int nn=0;nn<2;++nn)
      #pragma unroll
      for(int r=0;r<4;++r){
        int row = m0 + iw*64 + m*16 + lg*4 + r;
        int col = n0 + jw*32 + nn*16 + lr;
        C[(size_t)row*N + col] = acc[m][nn][r];
      }
}

// ------------- rmsnorm + rope -> fp16 Q (row-major) + fragment-major KVF -------------
// KVF per 32-key tile (10240 u16): K frags (ks*2+kj)*512 + lane*8 + e
//   holding K[key=kj*16+(lane&15)][d=ks*32+(lane>>4)*8+e];
// then V frags 4096 + df*512 + lane*8 + e holding Vt[d=df*16+(lane&15)][key=(lane>>4)*8+e].
__device__ __forceinline__ float blocksum128(float v, float* red, int t){
  #pragma unroll
  for (int m=32; m>=1; m>>=1) v += __shfl_xor(v, m, 64);
  __syncthreads();
  if ((t&63)==0) red[t>>6] = v;
  __syncthreads();
  return red[0] + red[1];
}

__global__ __launch_bounds__(128) void k_normrope(const float* __restrict__ qkv,
   const float* __restrict__ rot, const float* __restrict__ qw, const float* __restrict__ kw,
   const float* __restrict__ vw, u16* __restrict__ Qf, u16* __restrict__ KVF){
  __shared__ float buf[128];
  __shared__ float red[2];
  int n = blockIdx.x, t = threadIdx.x;
  const float* row = qkv + (size_t)n*1344;
  float pos = rot[(size_t)n*128 + t];
  float cs = cosf(pos), sn = sinf(pos);
  float qwt = qw[t], kwt = kw[t];
  size_t tbase = (size_t)(n>>5)*10240;
  #pragma unroll 1
  for (int h=0; h<8; ++h){
    float v = row[h*128 + t];
    float ss = blocksum128(v*v, red, t);
    float rr = rsqrtf(ss*(1.0f/128.0f) + 1.1920929e-07f);
    float qn = v*rr*qwt*0.125f;
    __syncthreads();
    buf[t] = qn;
    __syncthreads();
    float partner = (t<64) ? -buf[t+64] : buf[t-64];
    float o = qn*cs + partner*sn;
    Qf[((size_t)h*2048 + n)*128 + t] = f2h(o);
  }
  {
    float v = row[1024 + t];
    float ss = blocksum128(v*v, red, t);
    float rr = rsqrtf(ss*(1.0f/128.0f) + 1.1920929e-07f);
    float kn = v*rr*kwt;
    __syncthreads();
    buf[t] = kn;
    __syncthreads();
    float partner = (t<64) ? -buf[t+64] : buf[t-64];
    float o = kn*cs + partner*sn;
    // K fragment scatter
    size_t ka = tbase + (size_t)((t>>5)*2 + ((n>>4)&1))*512
              + (size_t)(((t>>3)&3)*16 + (n&15))*8 + (t&7);
    KVF[ka] = f2h(o);
  }
  {
    float v0 = row[1152 + t];
    float v1 = (t<64) ? row[1280 + t] : 0.0f;
    float ss = blocksum128(v0*v0 + v1*v1, red, t);
    float rr = rsqrtf(ss*(1.0f/192.0f) + 1.1920929e-07f);
    int lgv = (n>>3)&3, ev = n&7;
    size_t vbase = tbase + 4096;
    int d0 = t;
    KVF[vbase + (size_t)(d0>>4)*512 + (size_t)(lgv*16 + (d0&15))*8 + ev] = f2h(v0*rr*vw[d0]);
    if (t < 64){
      int d1 = 128 + t;
      KVF[vbase + (size_t)(d1>>4)*512 + (size_t)(lgv*16 + (d1&15))*8 + ev] = f2h(v1*rr*vw[d1]);
    }
  }
}

// ------------- pairwise -> attention bias v2: MFMA matvec, bias[pair][8] -------------
__global__ __launch_bounds__(256) void k_bias2(const float* __restrict__ pw, const float* __restrict__ rv,
  const float* __restrict__ gamma, const float* __restrict__ beta, const float* __restrict__ Wb,
  float* __restrict__ bias){
  __shared__ float As[128], Bs[128];
  int t = threadIdx.x;
  if (t < 128){
    As[t] = 11.313708498984761f * rsqrtf(fmaxf(rv[t], 1e-5f)) * (gamma[t] + 1.0f);
    Bs[t] = beta[t];
  }
  __syncthreads();
  int w = t>>6, lane = t&63, lg = lane>>4, lr = lane&15;
  s16x8 wbh[4], wbl[4];
  #pragma unroll
  for (int ks=0; ks<4; ++ks){
    s16x8 vh, vl;
    #pragma unroll
    for (int e=0; e<8; ++e){
      float v = (lr < 8) ? Wb[(ks*32 + lg*8 + e)*8 + lr] : 0.0f;
      u16 hh = f2bf(v);
      vh[e] = (short)hh;
      vl[e] = (short)f2bf(v - bf2f(hh));
    }
    wbh[ks] = vh; wbl[ks] = vl;
  }
  #pragma unroll
  for (int it=0; it<2; ++it){
    int p0 = blockIdx.x*128 + it*64 + w*16;
    const float* rowp = pw + (size_t)(p0 + lr)*128;
    f32x4 acc = {0.f,0.f,0.f,0.f};
    #pragma unroll
    for (int ks=0; ks<4; ++ks){
      int c = ks*32 + lg*8;
      float4 x0 = *(const float4*)(rowp + c);
      float4 x1 = *(const float4*)(rowp + c + 4);
      float4 a0 = *(const float4*)&As[c], a1 = *(const float4*)&As[c+4];
      float4 b0 = *(const float4*)&Bs[c], b1 = *(const float4*)&Bs[c+4];
      float xv[8] = {x0.x*a0.x+b0.x, x0.y*a0.y+b0.y, x0.z*a0.z+b0.z, x0.w*a0.w+b0.w,
                     x1.x*a1.x+b1.x, x1.y*a1.y+b1.y, x1.z*a1.z+b1.z, x1.w*a1.w+b1.w};
      s16x8 gh, gl;
      #pragma unroll
      for (int e=0; e<8; ++e){
        float v = xv[e];
        float z = v * 0.7071067811865476f;
        float s = fabsf(z);
        float tt = 1.0f / (1.0f + 0.3275911f*s);
        float poly = ((((1.061405429f*tt - 1.453152027f)*tt + 1.421413741f)*tt - 0.284496736f)*tt + 0.254829592f)*tt;
        float E = __expf(-s*s);
        float Q = 0.5f*v*poly*E;
        float ge = (v >= 0.0f) ? (v - Q) : Q;
        u16 hh = f2bf(ge);
        gh[e] = (short)hh;
        gl[e] = (short)f2bf(ge - bf2f(hh));
      }
      acc = mfma16(gh, wbh[ks], acc);
      acc = mfma16(gh, wbl[ks], acc);
      acc = mfma16(gl, wbh[ks], acc);
    }
    if (lr < 8)
      #pragma unroll
      for (int r=0; r<4; ++r)
        bias[(size_t)(p0 + lg*4 + r)*8 + lr] = acc[r];
  }
}

// ------------- fused attention v6: fragment-major K/V, gload_lds staging, -------------
// 4 waves = 4 GQA heads x Q=32, z=4 key split, f16 partials, ones-frag rowsums.
// LDS u16 map: KS dbuf [2][4096] @0 ; VS dbuf [2][6144] @8192 ; PS [4][1024] @20480.
__global__ __launch_bounds__(256,2) void k_attn6(const u16* __restrict__ Qf,
  const u16* __restrict__ KVF, const float* __restrict__ bias,
  u16* __restrict__ OP, float* __restrict__ SP){
  __shared__ u16 lds[24576];
  int t = threadIdx.x;
  int w = t>>6, lane = t&63, lg = lane>>4, lr = lane&15;
  int q0 = blockIdx.x*32;
  int h  = blockIdx.y*4 + w;
  int zi = blockIdx.z;
  // Q fragments (fp16), 2 q-subtiles
  f16x8 qf[2][4];
  #pragma unroll
  for (int qi=0; qi<2; ++qi){
    const u16* qb = Qf + ((size_t)h*2048 + q0 + qi*16 + lr)*128 + lg*8;
    #pragma unroll
    for (int ks=0; ks<4; ++ks) qf[qi][ks] = *(const f16x8*)(qb + ks*32);
  }
  const char* kvb = (const char*)KVF + (size_t)zi*16*20480;
  int wb = w*1024 + lane*16;
  auto stage = [&](int jt, int cur){
    const char* src = kvb + (size_t)jt*20480;
    // K: 8192 B -> KS[cur]
    gload16(src + wb,         &lds[cur*4096 + (w*1024>>1)]);
    gload16(src + 4096 + wb,  &lds[cur*4096 + 2048 + (w*1024>>1)]);
    // V: 12288 B -> VS[cur]
    gload16(src + 8192 + wb,  &lds[8192 + cur*6144 + (w*1024>>1)]);
    gload16(src + 12288 + wb, &lds[8192 + cur*6144 + 2048 + (w*1024>>1)]);
    gload16(src + 16384 + wb, &lds[8192 + cur*6144 + 4096 + (w*1024>>1)]);
  };
  // bias rows: (q>>2) = (q0>>2) + qi*4 + lg ; cols: (key>>2)
  float bCur[2][2], bNxt[2][2];
  auto loadBias = [&](int jt, float bb[2][2]){
    int jq = (zi*512 + jt*32)>>2;
    #pragma unroll
    for (int qi=0; qi<2; ++qi)
      #pragma unroll
      for (int kj=0; kj<2; ++kj)
        bb[qi][kj] = bias[((size_t)((q0>>2) + qi*4 + lg)*512 + jq + kj*4 + (lr>>2))*8 + h];
  };
  stage(0, 0);
  loadBias(0, bCur);
  __syncthreads();
  f32x4 accO[2][12] = {};
  f32x4 accR[2] = {};
  f16x8 vone;
  #pragma unroll
  for (int e=0; e<8; ++e) vone[e] = (_Float16)1.0f;
  int psb = 20480 + w*1024;
  int cur = 0;
  for (int jt=0; jt<16; ++jt){
    if (jt < 15){ stage(jt+1, cur^1); loadBias(jt+1, bNxt); }
    // QK^T: A=Q rows, B=K frags (conflict-free lane-linear reads)
    f32x4 accS[2][2] = {};
    #pragma unroll
    for (int ks=0; ks<4; ++ks){
      #pragma unroll
      for (int kj=0; kj<2; ++kj){
        f16x8 kb = *(const f16x8*)&lds[cur*4096 + (ks*2+kj)*512 + lane*8];
        accS[0][kj] = mfma16h(qf[0][ks], kb, accS[0][kj]);
        accS[1][kj] = mfma16h(qf[1][ks], kb, accS[1][kj]);
      }
    }
    // softcap softmax (scaled by e^-5: p' = exp(-10/(e^{0.4s}+1)) <= 1), pack P into A-frag slots
    #pragma unroll
    for (int qi=0; qi<2; ++qi)
      #pragma unroll
      for (int kj=0; kj<2; ++kj){
        float bv = bCur[qi][kj];
        #pragma unroll
        for (int r=0; r<4; ++r){
          float s = accS[qi][kj][r] + bv;
          float te = __expf(0.4f*s);
          float ri; asm("v_rcp_f32 %0, %1" : "=v"(ri) : "v"(te + 1.0f));
          float p = __expf(-10.0f*ri);
          // slot: lane' = (k>>3)*16 + (q&15), e' = k&7 ; q=qi*16+lg*4+r, k=kj*16+lr
          lds[psb + qi*512 + ((kj*2 + (lr>>3))*16 + lg*4 + r)*8 + (lr&7)] = f2h(p);
        }
      }
    f16x8 pa0 = *(const f16x8*)&lds[psb + lane*8];
    f16x8 pa1 = *(const f16x8*)&lds[psb + 512 + lane*8];
    // PV + ones-frag rowsum
    #pragma unroll
    for (int df=0; df<12; ++df){
      f16x8 vb = *(const f16x8*)&lds[8192 + cur*6144 + df*512 + lane*8];
      accO[0][df] = mfma16h(pa0, vb, accO[0][df]);
      accO[1][df] = mfma16h(pa1, vb, accO[1][df]);
    }
    accR[0] = mfma16h(pa0, vone, accR[0]);
    accR[1] = mfma16h(pa1, vone, accR[1]);
    __syncthreads();
    cur ^= 1;
    #pragma unroll
    for (int qi=0; qi<2; ++qi){ bCur[qi][0] = bNxt[qi][0]; bCur[qi][1] = bNxt[qi][1]; }
  }
  // write f16 partials + f32 rowsums
  #pragma unroll
  for (int qi=0; qi<2; ++qi){
    #pragma unroll
    for (int df=0; df<12; ++df)
      #pragma unroll
      for (int r=0; r<4; ++r){
        int q = q0 + qi*16 + lg*4 + r;
        OP[(((size_t)zi*8 + h)*2048 + q)*192 + df*16 + lr] = f2h(accO[qi][df][r]);
      }
    if (lr == 0)
      #pragma unroll
      for (int r=0; r<4; ++r)
        SP[((size_t)zi*8 + h)*2048 + q0 + qi*16 + lg*4 + r] = accR[qi][r];
  }
}

// ------------- combine 4 z-partials, normalize, relayout, bf16 hi/lo -------------
__global__ __launch_bounds__(256) void k_comb(const u16* __restrict__ OP,
    const float* __restrict__ SP, u16* __restrict__ Oh, u16* __restrict__ Ol){
  int id = blockIdx.x*256 + threadIdx.x;   // 8*2048*48
  int hq = id / 48;
  int d4 = (id - hq*48)*4;
  float inv = 1.0f / (SP[hq] + SP[16384+hq] + SP[32768+hq] + SP[49152+hq]);
  float o[4] = {0.f,0.f,0.f,0.f};
  #pragma unroll
  for (int z=0; z<4; ++z){
    ushort4 v = *(const ushort4*)&OP[((size_t)z*16384 + hq)*192 + d4];
    o[0] += h2f(v.x); o[1] += h2f(v.y); o[2] += h2f(v.z); o[3] += h2f(v.w);
  }
  int hh = hq >> 11, q = hq & 2047;
  size_t oo = (size_t)q*1536 + hh*192 + d4;
  u16 rh[4], rl[4];
  #pragma unroll
  for (int j=0; j<4; ++j){
    float v = o[j]*inv;
    rh[j] = f2bf(v);
    rl[j] = f2bf(v - bf2f(rh[j]));
  }
  *(ushort4*)(Oh+oo) = make_ushort4(rh[0],rh[1],rh[2],rh[3]);
  *(ushort4*)(Ol+oo) = make_ushort4(rl[0],rl[1],rl[2],rl[3]);
}

extern "C" void kernel_launch(void* const* d_in, const int* in_sizes, int n_in,
                              void* d_out, int out_size, void* d_ws, size_t ws_size,
                              hipStream_t stream){
  (void)in_sizes; (void)n_in; (void)out_size; (void)ws_size;
  const float* x   = (const float*)d_in[0];
  const float* pwi = (const float*)d_in[1];
  const float* rot = (const float*)d_in[2];
  const float* Wq  = (const float*)d_in[3];
  const float* qw  = (const float*)d_in[4];
  const float* kw  = (const float*)d_in[5];
  const float* vw  = (const float*)d_in[6];
  const float* gm  = (const float*)d_in[7];
  const float* bt  = (const float*)d_in[8];
  const float* rvv = (const float*)d_in[9];
  const float* Wb  = (const float*)d_in[10];
  const float* Wo  = (const float*)d_in[11];
  float* out = (float*)d_out;
  char* ws = (char*)d_ws;
  // Region A [0, 25165824): OP f16[4][8][2048][192], written by k_attn6.
  // It aliases xh/xl/Wqh/Wql/qkv, all dead before k_attn6 runs.
  u16*   OP  = (u16*)ws;
  u16*   xh  = (u16*)(ws + 0);
  u16*   xl  = (u16*)(ws + 4194304);
  u16*   Wqh = (u16*)(ws + 8388608);
  u16*   Wql = (u16*)(ws + 11141120);
  float* qkv = (float*)(ws + 13893632);    // ends 24903680 < 25165824
  size_t off = 25165824;
  auto alloc = [&](size_t bytes)->char*{
    char* p = ws + off; off = (off + bytes + 255) & ~(size_t)255; return p;
  };
  float* SP  = (float*)alloc(4ull*8*2048*4);
  u16* Woh = (u16*)alloc(1024ull*1536*2);
  u16* Wol = (u16*)alloc(1024ull*1536*2);
  u16* Qfb = (u16*)alloc(8ull*2048*128*2);
  u16* KVF = (u16*)alloc(64ull*10240*2);
  float* bias = (float*)alloc(8ull*512*512*4);   // layout [pair][8]
  u16* Ohb = (u16*)alloc(2048ull*1536*2);
  u16* Olb = (u16*)alloc(2048ull*1536*2);

  k_split<<<2048, 256, 0, stream>>>(x, xh, xl, 524288);
  k_tsplit<<<dim3(1344/32, 1024/32), 256, 0, stream>>>(Wq, Wqh, Wql, 1024, 1344);
  k_tsplit<<<dim3(1024/32, 1536/32), 256, 0, stream>>>(Wo, Woh, Wol, 1536, 1024);
  k_gemm<<<dim3(1344/64, 2048/128), 256, 0, stream>>>(xh, xl, Wqh, Wql, qkv, 2048, 1344, 1024);
  k_normrope<<<2048, 128, 0, stream>>>(qkv, rot, qw, kw, vw, Qfb, KVF);
  k_bias2<<<2048, 256, 0, stream>>>(pwi, rvv, gm, bt, Wb, bias);
  k_attn6<<<dim3(64, 2, 4), 256, 0, stream>>>(Qfb, KVF, bias, OP, SP);
  k_comb<<<3072, 256, 0, stream>>>(OP, SP, Ohb, Olb);
  k_gemm<<<dim3(1024/64, 2048/128), 256, 0, stream>>>(Ohb, Olb, Woh, Wol, out, 2048, 1024, 1536);
}

// Round 8
// 169.545 us; speedup vs baseline: 2.6903x; 1.0534x over previous
//
#include <hip/hip_runtime.h>
#include <math.h>

typedef unsigned short u16;
typedef __attribute__((ext_vector_type(4))) float f32x4;
typedef __attribute__((ext_vector_type(8))) short s16x8;
typedef __attribute__((ext_vector_type(8))) _Float16 f16x8;

__device__ __forceinline__ u16 f2bf(float f){
  unsigned u = __builtin_bit_cast(unsigned, f);
  u += 0x7fffu + ((u >> 16) & 1u);
  return (u16)(u >> 16);
}
__device__ __forceinline__ float bf2f(u16 h){
  unsigned u = ((unsigned)h) << 16;
  return __builtin_bit_cast(float, u);
}
__device__ __forceinline__ u16 f2h(float f){
  return __builtin_bit_cast(u16, (_Float16)f);
}
__device__ __forceinline__ float h2f(u16 h){
  return (float)__builtin_bit_cast(_Float16, h);
}
__device__ __forceinline__ f32x4 mfma16(s16x8 a, s16x8 b, f32x4 c){
  return __builtin_amdgcn_mfma_f32_16x16x32_bf16(a, b, c, 0, 0, 0);
}
__device__ __forceinline__ f32x4 mfma16h(f16x8 a, f16x8 b, f32x4 c){
  return __builtin_amdgcn_mfma_f32_16x16x32_f16(a, b, c, 0, 0, 0);
}
__device__ __forceinline__ void gload16(const void* src, const u16* ldsbase){
  __builtin_amdgcn_global_load_lds(
      (const __attribute__((address_space(1))) void*)src,
      (__attribute__((address_space(3))) void*)ldsbase, 16, 0, 0);
}

// ---- x (2048x1024 f32) -> fragment-major bf16 hi/lo A-tiles [mt][kt] 16384 u16 each ----
// tile layout: [hl][ks2][ms][lane][8], lane = lg*16 + m16,
// element = A[mt*128+ms*16+m16][kt*64+ks2*32+lg*8+e]
__global__ __launch_bounds__(256) void k_split2(const float* __restrict__ x,
    u16* __restrict__ Afq){
  int id = blockIdx.x*256 + threadIdx.x;      // 262144
  int row = id>>7, k0 = (id&127)*8;
  const float4* xp = (const float4*)(x + (size_t)row*1024 + k0);
  float4 v0 = xp[0], v1 = xp[1];
  float vv[8] = {v0.x,v0.y,v0.z,v0.w, v1.x,v1.y,v1.z,v1.w};
  u16 hh[8], ll[8];
  #pragma unroll
  for (int e=0; e<8; ++e){ hh[e] = f2bf(vv[e]); ll[e] = f2bf(vv[e] - bf2f(hh[e])); }
  int mt = row>>7, ms = (row>>4)&7, m16 = row&15;
  int kt = k0>>6, ks2 = (k0>>5)&1, lg = (k0>>3)&3;
  int lane = lg*16 + m16;
  size_t base = (size_t)(mt*16 + kt)*16384;
  *(uint4*)&Afq[base + (size_t)(ks2*8 + ms)*512 + lane*8]      = *(uint4*)hh;
  *(uint4*)&Afq[base + (size_t)((2+ks2)*8 + ms)*512 + lane*8]  = *(uint4*)ll;
}

// ---- W (K x N f32, row-major) -> fragment-major bf16 hi/lo B-tiles [nt][kt] 8192 u16 ----
// tile layout: [hl][ks2][ns][lane][8], lane = lg*16 + n16,
// element = W[kt*64+ks2*32+lg*8+e][nt*64+ns*16+n16]
__global__ __launch_bounds__(256) void k_tsplit2(const float* __restrict__ in,
    u16* __restrict__ Bfq, int N, int nKt){
  __shared__ float tile[64][65];
  int t = threadIdx.x;
  int nt = blockIdx.x, kt = blockIdx.y;
  #pragma unroll
  for (int i=0; i<16; ++i){
    int idx = i*256 + t;
    int r = idx>>6, c = idx&63;
    tile[r][c] = in[(size_t)(kt*64 + r)*N + nt*64 + c];
  }
  __syncthreads();
  size_t base = (size_t)(nt*nKt + kt)*8192;
  #pragma unroll
  for (int j=0; j<2; ++j){
    int idx = j*256 + t;
    int np = idx>>3, ko = idx&7;
    u16 hh[8], ll[8];
    #pragma unroll
    for (int e=0; e<8; ++e){
      float v = tile[ko*8+e][np];
      hh[e] = f2bf(v); ll[e] = f2bf(v - bf2f(hh[e]));
    }
    int ks2 = ko>>2, lg = ko&3, ns = np>>4, n16 = np&15;
    int lane = lg*16 + n16;
    *(uint4*)&Bfq[base + (size_t)(ks2*4 + ns)*512 + lane*8]     = *(uint4*)hh;
    *(uint4*)&Bfq[base + (size_t)((2+ks2)*4 + ns)*512 + lane*8] = *(uint4*)ll;
  }
}

// ---- fragment-major split-bf16 GEMM, gload_lds staging, 128x64 tile, BK=64 ----
// C[M][N] = A x B^T, 3-term compensated. LDS: A tile 16384 u16 @0, B tile 8192 @16384.
__global__ __launch_bounds__(256,3) void k_gemm2(const u16* __restrict__ Afq,
    const u16* __restrict__ Bfq, float* __restrict__ C, int N, int nKt){
  __shared__ u16 lds[24576];
  int t = threadIdx.x;
  int w = t>>6, lane = t&63, lg = lane>>4, lr = lane&15;
  int iw = w&1, jw = w>>1;
  int n0 = blockIdx.x*64, m0 = blockIdx.y*128;
  const char* srcA = (const char*)(Afq + (size_t)blockIdx.y*nKt*16384);
  const char* srcB = (const char*)(Bfq + (size_t)blockIdx.x*nKt*8192);
  int wb = w*1024 + lane*16;
  f32x4 acc[4][2] = {};
  for (int kt=0; kt<nKt; ++kt){
    __syncthreads();                       // done reading prev tile
    const char* ta = srcA + (size_t)kt*32768;
    const char* tb = srcB + (size_t)kt*16384;
    #pragma unroll
    for (int i=0; i<8; ++i)
      gload16(ta + i*4096 + wb, &lds[(i*4096 + w*1024)>>1]);
    #pragma unroll
    for (int i=0; i<4; ++i)
      gload16(tb + i*4096 + wb, &lds[16384 + ((i*4096 + w*1024)>>1)]);
    __syncthreads();                       // vmcnt(0) drained -> tile visible
    #pragma unroll
    for (int ks2=0; ks2<2; ++ks2){
      s16x8 ah[4], al[4], bh[2], bl[2];
      #pragma unroll
      for (int m=0; m<4; ++m){
        ah[m] = *(const s16x8*)&lds[(size_t)(ks2*8 + iw*4 + m)*512 + lane*8];
        al[m] = *(const s16x8*)&lds[(size_t)((2+ks2)*8 + iw*4 + m)*512 + lane*8];
      }
      #pragma unroll
      for (int n=0; n<2; ++n){
        bh[n] = *(const s16x8*)&lds[16384 + (size_t)(ks2*4 + jw*2 + n)*512 + lane*8];
        bl[n] = *(const s16x8*)&lds[16384 + (size_t)((2+ks2)*4 + jw*2 + n)*512 + lane*8];
      }
      #pragma unroll
      for (int m=0; m<4; ++m)
        #pragma unroll
        for (int n=0; n<2; ++n){
          acc[m][n] = mfma16(ah[m], bh[n], acc[m][n]);
          acc[m][n] = mfma16(ah[m], bl[n], acc[m][n]);
          acc[m][n] = mfma16(al[m], bh[n], acc[m][n]);
        }
    }
  }
  #pragma unroll
  for (int m=0; m<4; ++m)
    #pragma unroll
    for (int n=0; n<2; ++n)
      #pragma unroll
      for (int r=0; r<4; ++r){
        int row = m0 + iw*64 + m*16 + lg*4 + r;
        int col = n0 + jw*32 + n*16 + lr;
        C[(size_t)row*N + col] = acc[m][n][r];
      }
}

// ------------- rmsnorm + rope -> fp16 Q (row-major) + fragment-major KVF -------------
__device__ __forceinline__ float blocksum128(float v, float* red, int t){
  #pragma unroll
  for (int m=32; m>=1; m>>=1) v += __shfl_xor(v, m, 64);
  __syncthreads();
  if ((t&63)==0) red[t>>6] = v;
  __syncthreads();
  return red[0] + red[1];
}

__global__ __launch_bounds__(128) void k_normrope(const float* __restrict__ qkv,
   const float* __restrict__ rot, const float* __restrict__ qw, const float* __restrict__ kw,
   const float* __restrict__ vw, u16* __restrict__ Qf, u16* __restrict__ KVF){
  __shared__ float buf[128];
  __shared__ float red[2];
  int n = blockIdx.x, t = threadIdx.x;
  const float* row = qkv + (size_t)n*1344;
  float pos = rot[(size_t)n*128 + t];
  float cs = cosf(pos), sn = sinf(pos);
  float qwt = qw[t], kwt = kw[t];
  size_t tbase = (size_t)(n>>5)*10240;
  #pragma unroll 1
  for (int h=0; h<8; ++h){
    float v = row[h*128 + t];
    float ss = blocksum128(v*v, red, t);
    float rr = rsqrtf(ss*(1.0f/128.0f) + 1.1920929e-07f);
    float qn = v*rr*qwt*0.125f;
    __syncthreads();
    buf[t] = qn;
    __syncthreads();
    float partner = (t<64) ? -buf[t+64] : buf[t-64];
    float o = qn*cs + partner*sn;
    Qf[((size_t)h*2048 + n)*128 + t] = f2h(o);
  }
  {
    float v = row[1024 + t];
    float ss = blocksum128(v*v, red, t);
    float rr = rsqrtf(ss*(1.0f/128.0f) + 1.1920929e-07f);
    float kn = v*rr*kwt;
    __syncthreads();
    buf[t] = kn;
    __syncthreads();
    float partner = (t<64) ? -buf[t+64] : buf[t-64];
    float o = kn*cs + partner*sn;
    size_t ka = tbase + (size_t)((t>>5)*2 + ((n>>4)&1))*512
              + (size_t)(((t>>3)&3)*16 + (n&15))*8 + (t&7);
    KVF[ka] = f2h(o);
  }
  {
    float v0 = row[1152 + t];
    float v1 = (t<64) ? row[1280 + t] : 0.0f;
    float ss = blocksum128(v0*v0 + v1*v1, red, t);
    float rr = rsqrtf(ss*(1.0f/192.0f) + 1.1920929e-07f);
    int lgv = (n>>3)&3, ev = n&7;
    size_t vbase = tbase + 4096;
    int d0 = t;
    KVF[vbase + (size_t)(d0>>4)*512 + (size_t)(lgv*16 + (d0&15))*8 + ev] = f2h(v0*rr*vw[d0]);
    if (t < 64){
      int d1 = 128 + t;
      KVF[vbase + (size_t)(d1>>4)*512 + (size_t)(lgv*16 + (d1&15))*8 + ev] = f2h(v1*rr*vw[d1]);
    }
  }
}

// ------------- pairwise -> attention bias v2: MFMA matvec, bias[pair][8] -------------
__global__ __launch_bounds__(256) void k_bias2(const float* __restrict__ pw, const float* __restrict__ rv,
  const float* __restrict__ gamma, const float* __restrict__ beta, const float* __restrict__ Wb,
  float* __restrict__ bias){
  __shared__ float As[128], Bs[128];
  int t = threadIdx.x;
  if (t < 128){
    As[t] = 11.313708498984761f * rsqrtf(fmaxf(rv[t], 1e-5f)) * (gamma[t] + 1.0f);
    Bs[t] = beta[t];
  }
  __syncthreads();
  int w = t>>6, lane = t&63, lg = lane>>4, lr = lane&15;
  s16x8 wbh[4], wbl[4];
  #pragma unroll
  for (int ks=0; ks<4; ++ks){
    s16x8 vh, vl;
    #pragma unroll
    for (int e=0; e<8; ++e){
      float v = (lr < 8) ? Wb[(ks*32 + lg*8 + e)*8 + lr] : 0.0f;
      u16 hh = f2bf(v);
      vh[e] = (short)hh;
      vl[e] = (short)f2bf(v - bf2f(hh));
    }
    wbh[ks] = vh; wbl[ks] = vl;
  }
  #pragma unroll
  for (int it=0; it<2; ++it){
    int p0 = blockIdx.x*128 + it*64 + w*16;
    const float* rowp = pw + (size_t)(p0 + lr)*128;
    f32x4 acc = {0.f,0.f,0.f,0.f};
    #pragma unroll
    for (int ks=0; ks<4; ++ks){
      int c = ks*32 + lg*8;
      float4 x0 = *(const float4*)(rowp + c);
      float4 x1 = *(const float4*)(rowp + c + 4);
      float4 a0 = *(const float4*)&As[c], a1 = *(const float4*)&As[c+4];
      float4 b0 = *(const float4*)&Bs[c], b1 = *(const float4*)&Bs[c+4];
      float xv[8] = {x0.x*a0.x+b0.x, x0.y*a0.y+b0.y, x0.z*a0.z+b0.z, x0.w*a0.w+b0.w,
                     x1.x*a1.x+b1.x, x1.y*a1.y+b1.y, x1.z*a1.z+b1.z, x1.w*a1.w+b1.w};
      s16x8 gh, gl;
      #pragma unroll
      for (int e=0; e<8; ++e){
        float v = xv[e];
        float z = v * 0.7071067811865476f;
        float s = fabsf(z);
        float tt = 1.0f / (1.0f + 0.3275911f*s);
        float poly = ((((1.061405429f*tt - 1.453152027f)*tt + 1.421413741f)*tt - 0.284496736f)*tt + 0.254829592f)*tt;
        float E = __expf(-s*s);
        float Q = 0.5f*v*poly*E;
        float ge = (v >= 0.0f) ? (v - Q) : Q;
        u16 hh = f2bf(ge);
        gh[e] = (short)hh;
        gl[e] = (short)f2bf(ge - bf2f(hh));
      }
      acc = mfma16(gh, wbh[ks], acc);
      acc = mfma16(gh, wbl[ks], acc);
      acc = mfma16(gl, wbh[ks], acc);
    }
    if (lr < 8)
      #pragma unroll
      for (int r=0; r<4; ++r)
        bias[(size_t)(p0 + lg*4 + r)*8 + lr] = acc[r];
  }
}

// ------------- fused attention v6: fragment-major K/V, gload_lds staging -------------
__global__ __launch_bounds__(256,2) void k_attn6(const u16* __restrict__ Qf,
  const u16* __restrict__ KVF, const float* __restrict__ bias,
  u16* __restrict__ OP, float* __restrict__ SP){
  __shared__ u16 lds[24576];
  int t = threadIdx.x;
  int w = t>>6, lane = t&63, lg = lane>>4, lr = lane&15;
  int q0 = blockIdx.x*32;
  int h  = blockIdx.y*4 + w;
  int zi = blockIdx.z;
  f16x8 qf[2][4];
  #pragma unroll
  for (int qi=0; qi<2; ++qi){
    const u16* qb = Qf + ((size_t)h*2048 + q0 + qi*16 + lr)*128 + lg*8;
    #pragma unroll
    for (int ks=0; ks<4; ++ks) qf[qi][ks] = *(const f16x8*)(qb + ks*32);
  }
  const char* kvb = (const char*)KVF + (size_t)zi*16*20480;
  int wb = w*1024 + lane*16;
  auto stage = [&](int jt, int cur){
    const char* src = kvb + (size_t)jt*20480;
    gload16(src + wb,         &lds[cur*4096 + (w*1024>>1)]);
    gload16(src + 4096 + wb,  &lds[cur*4096 + 2048 + (w*1024>>1)]);
    gload16(src + 8192 + wb,  &lds[8192 + cur*6144 + (w*1024>>1)]);
    gload16(src + 12288 + wb, &lds[8192 + cur*6144 + 2048 + (w*1024>>1)]);
    gload16(src + 16384 + wb, &lds[8192 + cur*6144 + 4096 + (w*1024>>1)]);
  };
  float bCur[2][2], bNxt[2][2];
  auto loadBias = [&](int jt, float bb[2][2]){
    int jq = (zi*512 + jt*32)>>2;
    #pragma unroll
    for (int qi=0; qi<2; ++qi)
      #pragma unroll
      for (int kj=0; kj<2; ++kj)
        bb[qi][kj] = bias[((size_t)((q0>>2) + qi*4 + lg)*512 + jq + kj*4 + (lr>>2))*8 + h];
  };
  stage(0, 0);
  loadBias(0, bCur);
  __syncthreads();
  f32x4 accO[2][12] = {};
  f32x4 accR[2] = {};
  f16x8 vone;
  #pragma unroll
  for (int e=0; e<8; ++e) vone[e] = (_Float16)1.0f;
  int psb = 20480 + w*1024;
  int cur = 0;
  for (int jt=0; jt<16; ++jt){
    if (jt < 15){ stage(jt+1, cur^1); loadBias(jt+1, bNxt); }
    f32x4 accS[2][2] = {};
    #pragma unroll
    for (int ks=0; ks<4; ++ks){
      #pragma unroll
      for (int kj=0; kj<2; ++kj){
        f16x8 kb = *(const f16x8*)&lds[cur*4096 + (ks*2+kj)*512 + lane*8];
        accS[0][kj] = mfma16h(qf[0][ks], kb, accS[0][kj]);
        accS[1][kj] = mfma16h(qf[1][ks], kb, accS[1][kj]);
      }
    }
    #pragma unroll
    for (int qi=0; qi<2; ++qi)
      #pragma unroll
      for (int kj=0; kj<2; ++kj){
        float bv = bCur[qi][kj];
        #pragma unroll
        for (int r=0; r<4; ++r){
          float s = accS[qi][kj][r] + bv;
          float te = __expf(0.4f*s);
          float ri; asm("v_rcp_f32 %0, %1" : "=v"(ri) : "v"(te + 1.0f));
          float p = __expf(-10.0f*ri);
          lds[psb + qi*512 + ((kj*2 + (lr>>3))*16 + lg*4 + r)*8 + (lr&7)] = f2h(p);
        }
      }
    f16x8 pa0 = *(const f16x8*)&lds[psb + lane*8];
    f16x8 pa1 = *(const f16x8*)&lds[psb + 512 + lane*8];
    #pragma unroll
    for (int df=0; df<12; ++df){
      f16x8 vb = *(const f16x8*)&lds[8192 + cur*6144 + df*512 + lane*8];
      accO[0][df] = mfma16h(pa0, vb, accO[0][df]);
      accO[1][df] = mfma16h(pa1, vb, accO[1][df]);
    }
    accR[0] = mfma16h(pa0, vone, accR[0]);
    accR[1] = mfma16h(pa1, vone, accR[1]);
    __syncthreads();
    cur ^= 1;
    #pragma unroll
    for (int qi=0; qi<2; ++qi){ bCur[qi][0] = bNxt[qi][0]; bCur[qi][1] = bNxt[qi][1]; }
  }
  #pragma unroll
  for (int qi=0; qi<2; ++qi){
    #pragma unroll
    for (int df=0; df<12; ++df)
      #pragma unroll
      for (int r=0; r<4; ++r){
        int q = q0 + qi*16 + lg*4 + r;
        OP[(((size_t)zi*8 + h)*2048 + q)*192 + df*16 + lr] = f2h(accO[qi][df][r]);
      }
    if (lr == 0)
      #pragma unroll
      for (int r=0; r<4; ++r)
        SP[((size_t)zi*8 + h)*2048 + q0 + qi*16 + lg*4 + r] = accR[qi][r];
  }
}

// ---- combine 4 z-partials, normalize, write fragment-major A-tiles for gemm2 ----
// attn-out matrix: M=2048 (q), K=1536 (col = h*192 + d). nKt = 24.
__global__ __launch_bounds__(256) void k_comb2(const u16* __restrict__ OP,
    const float* __restrict__ SP, u16* __restrict__ Ao2){
  int id = blockIdx.x*256 + threadIdx.x;    // 8*2048*24 = 393216
  int hq = id / 24;
  int oct = id - hq*24;
  int d0 = oct*8;
  float inv = 1.0f / (SP[hq] + SP[16384+hq] + SP[32768+hq] + SP[49152+hq]);
  float o[8] = {0,0,0,0,0,0,0,0};
  #pragma unroll
  for (int z=0; z<4; ++z){
    uint4 v = *(const uint4*)&OP[((size_t)z*16384 + hq)*192 + d0];
    const u16* pv = (const u16*)&v;
    #pragma unroll
    for (int e=0; e<8; ++e) o[e] += h2f(pv[e]);
  }
  int h = hq >> 11, q = hq & 2047;
  int col = h*192 + d0;
  int kt = col>>6, ks2 = (col>>5)&1, lg = (col>>3)&3;
  int mt = q>>7, ms = (q>>4)&7, m16 = q&15;
  int lane = lg*16 + m16;
  u16 hh[8], ll[8];
  #pragma unroll
  for (int e=0; e<8; ++e){
    float v = o[e]*inv;
    hh[e] = f2bf(v); ll[e] = f2bf(v - bf2f(hh[e]));
  }
  size_t base = (size_t)(mt*24 + kt)*16384;
  *(uint4*)&Ao2[base + (size_t)(ks2*8 + ms)*512 + lane*8]     = *(uint4*)hh;
  *(uint4*)&Ao2[base + (size_t)((2+ks2)*8 + ms)*512 + lane*8] = *(uint4*)ll;
}

extern "C" void kernel_launch(void* const* d_in, const int* in_sizes, int n_in,
                              void* d_out, int out_size, void* d_ws, size_t ws_size,
                              hipStream_t stream){
  (void)in_sizes; (void)n_in; (void)out_size; (void)ws_size;
  const float* x   = (const float*)d_in[0];
  const float* pwi = (const float*)d_in[1];
  const float* rot = (const float*)d_in[2];
  const float* Wq  = (const float*)d_in[3];
  const float* qw  = (const float*)d_in[4];
  const float* kw  = (const float*)d_in[5];
  const float* vw  = (const float*)d_in[6];
  const float* gm  = (const float*)d_in[7];
  const float* bt  = (const float*)d_in[8];
  const float* rvv = (const float*)d_in[9];
  const float* Wb  = (const float*)d_in[10];
  const float* Wo  = (const float*)d_in[11];
  float* out = (float*)d_out;
  char* ws = (char*)d_ws;
  size_t off = 0;
  auto alloc = [&](size_t bytes)->char*{
    char* p = ws + off; off = (off + bytes + 255) & ~(size_t)255; return p;
  };
  u16*   Axq = (u16*)alloc(16ull*16*16384*2);     // x frag-major (8 MB)
  u16*   Bq1 = (u16*)alloc(21ull*16*8192*2);      // Wqkv frag-major (5.5 MB)
  u16*   Bq2 = (u16*)alloc(16ull*24*8192*2);      // Wo frag-major (6.3 MB)
  u16*   Ao2 = (u16*)alloc(16ull*24*16384*2);     // attn-out frag-major (12.6 MB)
  float* qkv = (float*)alloc(2048ull*1344*4);
  u16*   Qfb = (u16*)alloc(8ull*2048*128*2);
  u16*   KVF = (u16*)alloc(64ull*10240*2);
  float* bias = (float*)alloc(8ull*512*512*4);    // layout [pair][8]
  u16*   OP  = (u16*)alloc(4ull*8*2048*192*2);
  float* SP  = (float*)alloc(4ull*8*2048*4);

  k_split2<<<1024, 256, 0, stream>>>(x, Axq);
  k_tsplit2<<<dim3(21, 16), 256, 0, stream>>>(Wq, Bq1, 1344, 16);
  k_tsplit2<<<dim3(16, 24), 256, 0, stream>>>(Wo, Bq2, 1024, 24);
  k_gemm2<<<dim3(21, 16), 256, 0, stream>>>(Axq, Bq1, qkv, 1344, 16);
  k_normrope<<<2048, 128, 0, stream>>>(qkv, rot, qw, kw, vw, Qfb, KVF);
  k_bias2<<<2048, 256, 0, stream>>>(pwi, rvv, gm, bt, Wb, bias);
  k_attn6<<<dim3(64, 2, 4), 256, 0, stream>>>(Qfb, KVF, bias, OP, SP);
  k_comb2<<<1536, 256, 0, stream>>>(OP, SP, Ao2);
  k_gemm2<<<dim3(16, 16), 256, 0, stream>>>(Ao2, Bq2, out, 1024, 24);
}